// Round 4
// baseline (3528.164 us; speedup 1.0000x reference)
//
#include <hip/hip_runtime.h>
#include <hip/hip_bf16.h>
#include <cstdint>
#include <cstddef>

#define B_   512
#define T_   128
#define D_   512
#define H_   512
#define MID_ 38
#define BOT_ 38
#define S_   26
#define XL_  588   // D + MID + BOT = W_ih row length

typedef unsigned short u16;
typedef __attribute__((ext_vector_type(8))) short bf16x8v;
typedef __attribute__((ext_vector_type(8))) unsigned short u16x8;
typedef __attribute__((ext_vector_type(4))) float f32x4v;

__device__ __forceinline__ float sigmoidf_(float x){ return 1.0f/(1.0f+expf(-x)); }
__device__ __forceinline__ u16 f2bf_rn(float f){
  unsigned u = __float_as_uint(f);
  return (u16)((u + 0x7fffu + ((u>>16)&1u)) >> 16);
}
__device__ __forceinline__ float bf2f(u16 v){ return __uint_as_float(((unsigned)v)<<16); }

// ---------------------------------------------------------------------------
// fp32 -> bf16 hi/lo plane decomposition (lo nullable), 512-col chunks,
// dest leading dim dld.  rows >= `rows` are zero-padded up to padrows.
// ---------------------------------------------------------------------------
__global__ __launch_bounds__(256) void cvt_plane(
    const float* __restrict__ src, int ld, int rows, int padrows, int dld,
    u16* __restrict__ hi, u16* __restrict__ lo)
{
  const int n4 = padrows*128;
  for (int i = blockIdx.x*256 + threadIdx.x; i < n4; i += gridDim.x*256){
    const int row = i >> 7, c4 = (i & 127)*4;
    float4 v = make_float4(0.f,0.f,0.f,0.f);
    if (row < rows) v = *(const float4*)&src[(size_t)row*ld + c4];
    ushort4 h;
    h.x=f2bf_rn(v.x); h.y=f2bf_rn(v.y); h.z=f2bf_rn(v.z); h.w=f2bf_rn(v.w);
    *(ushort4*)&hi[(size_t)row*dld + c4] = h;
    if (lo){
      ushort4 l;
      l.x=f2bf_rn(v.x-bf2f(h.x)); l.y=f2bf_rn(v.y-bf2f(h.y));
      l.z=f2bf_rn(v.z-bf2f(h.z)); l.w=f2bf_rn(v.w-bf2f(h.w));
      *(ushort4*)&lo[(size_t)row*dld + c4] = l;
    }
  }
}

// token-column tables, transposed for coalesced epilogue reads
__global__ __launch_bounds__(256) void build_tokT(
    const float* __restrict__ Wih, float* __restrict__ WmT, float* __restrict__ WbT)
{
  int i = blockIdx.x*256 + threadIdx.x;   // over 38*2048
  if (i < MID_*2048){
    int c = i >> 11, j = i & 2047;
    WmT[i] = Wih[(size_t)j*XL_ + 512 + c];
    WbT[i] = Wih[(size_t)j*XL_ + 512 + MID_ + c];
  }
}

// bcomb2[j] = b_ih[j] + b_hh[j], j in [0,2048)
__global__ __launch_bounds__(256) void bcomb_kernel(
    const float* __restrict__ bih, const float* __restrict__ bhh,
    float* __restrict__ o)
{
  int i = blockIdx.x*256 + threadIdx.x;
  if (i < 2048) o[i] = bih[i] + bhh[i];
}

// 512x512 fp32 transpose (for coalesced pp GEMV): WT[k][j] = W[j][k]
__global__ __launch_bounds__(256) void transpose512(
    const float* __restrict__ W, float* __restrict__ WT)
{
  __shared__ float t[32][33];
  const int bx = blockIdx.x*32, by = blockIdx.y*32;
  const int x = threadIdx.x & 31, y = threadIdx.x >> 5;   // 32 x 8
  for (int yy=y; yy<32; yy+=8) t[yy][x] = W[(size_t)(by+yy)*512 + bx+x];
  __syncthreads();
  for (int yy=y; yy<32; yy+=8) WT[(size_t)(bx+yy)*512 + by+x] = t[x][yy];
}

// ---------------------------------------------------------------------------
// Pure-bf16 MFMA GEMM (used for proj and generator), K = kSteps*32, NT.
// npass=1: hi*hi.  npass=3: bf16x2 (hi*hi + hi*lo + lo*hi).
// MODE 1: bf16 out via LDS bounce.  MODE 2: generator out (m->(s,b), n<38,
// +bias2).
// ---------------------------------------------------------------------------
template<int BM,int BN,int MODE>
__global__ __launch_bounds__(256) void gemm_bf(
    const u16* __restrict__ Ah, const u16* __restrict__ Al, int lda,
    const u16* __restrict__ Bh, const u16* __restrict__ Bl, int ldb,
    u16* __restrict__ CoutB, float* __restrict__ Cout, int ldc,
    const float* __restrict__ bias2, int npass, int kSteps)
{
  extern __shared__ char smem[];
  constexpr int STR = 40;                    // padded LDS stride (shorts)
  short* As = (short*)smem;                  // [BM][STR]
  short* Bs = As + BM*STR;                   // [BN][STR]
  const int tid=threadIdx.x, bm=blockIdx.y*BM, bn=blockIdx.x*BN;
  const int w=tid>>6, lane=tid&63, wr=w>>1, wc=w&1;
  constexpr int WM=BM/2, WN=BN/2, FM=WM/16, FN=WN/16;
  constexpr int LA=BM/64, LB=BN/64;          // 16B chunks per thread
  const int nIter = npass*kSteps;

  f32x4v acc[FM][FN];
#pragma unroll
  for (int i=0;i<FM;i++)
#pragma unroll
    for (int j=0;j<FN;j++) acc[i][j] = (f32x4v){0.f,0.f,0.f,0.f};

  u16x8 ra[LA], rb[LB];
  auto load = [&](int it){
    const int pass = it/kSteps, kk = (it%kSteps)<<5;
    const u16* Ap = (pass==2)?Al:Ah;
    const u16* Bp = (pass==1)?Bl:Bh;
#pragma unroll
    for (int L=0; L<LA; L++){
      int t=L*256+tid, row=t>>2, c=(t&3)*8;
      ra[L] = *(const u16x8*)&Ap[(size_t)(bm+row)*lda + kk + c];
    }
#pragma unroll
    for (int L=0; L<LB; L++){
      int t=L*256+tid, row=t>>2, c=(t&3)*8;
      rb[L] = *(const u16x8*)&Bp[(size_t)(bn+row)*ldb + kk + c];
    }
  };
  load(0);

  for (int it=0; it<nIter; ++it){
    __syncthreads();
#pragma unroll
    for (int L=0; L<LA; L++){ int t=L*256+tid; *(u16x8*)&As[(t>>2)*STR+(t&3)*8] = ra[L]; }
#pragma unroll
    for (int L=0; L<LB; L++){ int t=L*256+tid; *(u16x8*)&Bs[(t>>2)*STR+(t&3)*8] = rb[L]; }
    if (it+1 < nIter) load(it+1);
    __syncthreads();
    bf16x8v af[FM], bfr[FN];
    const int koff = (lane>>4)*8, mrow = lane&15;
#pragma unroll
    for (int i=0;i<FM;i++) af[i]  = *(const bf16x8v*)&As[(wr*WM+i*16+mrow)*STR + koff];
#pragma unroll
    for (int j=0;j<FN;j++) bfr[j] = *(const bf16x8v*)&Bs[(wc*WN+j*16+mrow)*STR + koff];
#pragma unroll
    for (int i=0;i<FM;i++)
#pragma unroll
      for (int j=0;j<FN;j++)
        acc[i][j] = __builtin_amdgcn_mfma_f32_16x16x32_bf16(af[i], bfr[j], acc[i][j], 0,0,0);
  }

  // C/D layout (m89): col = lane&15, row = (lane>>4)*4 + r.
  const int r0 = (lane>>4)*4, cn = lane&15;
  if constexpr (MODE==1){
    __syncthreads();
    u16* Ts = (u16*)smem;   // [BM][BN] bf16 bounce
#pragma unroll
    for (int i=0;i<FM;i++)
#pragma unroll
      for (int j=0;j<FN;j++)
#pragma unroll
        for (int r=0;r<4;r++)
          Ts[(wr*WM+i*16+r0+r)*BN + wc*WN+j*16+cn] = f2bf_rn(acc[i][j][r]);
    __syncthreads();
#pragma unroll
    for (int q=0;q<(BM*BN/8)/256;q++){
      int idx = q*256 + tid;
      int row = idx/(BN/8), c8 = (idx%(BN/8))*8;
      *(float4*)&CoutB[(size_t)(bm+row)*ldc + bn + c8] = *(const float4*)&Ts[row*BN + c8];
    }
  } else {
#pragma unroll
    for (int i=0;i<FM;i++)
#pragma unroll
      for (int j=0;j<FN;j++)
#pragma unroll
        for (int r=0;r<4;r++){
          int m = bm + wr*WM + i*16 + r0 + r;       // m = s*512 + b
          int n = bn + wc*WN + j*16 + cn;
          if (n < MID_){
            int s = m >> 9, b = m & 511;
            Cout[((size_t)b*S_ + s)*MID_ + n] = acc[i][j][r] + bias2[n];
          }
        }
  }
}

// ---------------------------------------------------------------------------
// Fused attention with pp head:
//   pp[j] = h[b,:].W_h2hT[:,j] + b_h2h[j]    (exact fp32 GEMV, WT layout)
//   e[t]  = sum_h Ws[h]*tanh(projb[b,t,h]+pp[h]); softmax over t;
//   ctx[b,d] = sum_t alpha[t]*bH[b,t,d] (fp32) -> Acat hi/lo cols 0..511.
// ---------------------------------------------------------------------------
__global__ __launch_bounds__(256) void attn_kernel(
    const u16* __restrict__ projb, const float* __restrict__ hf,
    const float* __restrict__ WT, const float* __restrict__ bh2h,
    const float* __restrict__ Wscore, const float* __restrict__ bH,
    u16* __restrict__ Acat_hi, u16* __restrict__ Acat_lo)
{
  __shared__ float s_h[H_];
  __shared__ float s_pp[H_];
  __shared__ float s_e[T_];
  __shared__ float s_red[8];
  __shared__ float s_part[4][D_];
  const int tid=threadIdx.x, b=blockIdx.x, wave=tid>>6, lane=tid&63;
  {
    float2 hv = *(const float2*)&hf[(size_t)b*H_ + tid*2];
    *(float2*)&s_h[tid*2] = hv;
  }
  __syncthreads();
  // pp GEMV: thread computes j = tid and tid+256 (coalesced WT column walk)
  {
    float a0 = bh2h[tid], a1 = bh2h[tid+256];
#pragma unroll 4
    for (int k=0;k<H_;k++){
      const float hk = s_h[k];
      a0 += hk * WT[(size_t)k*512 + tid];
      a1 += hk * WT[(size_t)k*512 + tid + 256];
    }
    s_pp[tid] = a0; s_pp[tid+256] = a1;
  }
  __syncthreads();
  float pv[8], wv[8];
  {
    float4 p0=*(const float4*)&s_pp[lane*8], p1=*(const float4*)&s_pp[lane*8+4];
    float4 w0=*(const float4*)&Wscore[lane*8], w1=*(const float4*)&Wscore[lane*8+4];
    pv[0]=p0.x;pv[1]=p0.y;pv[2]=p0.z;pv[3]=p0.w;pv[4]=p1.x;pv[5]=p1.y;pv[6]=p1.z;pv[7]=p1.w;
    wv[0]=w0.x;wv[1]=w0.y;wv[2]=w0.z;wv[3]=w0.w;wv[4]=w1.x;wv[5]=w1.y;wv[6]=w1.z;wv[7]=w1.w;
  }
  for (int t=wave; t<T_; t+=4){
    u16x8 vv = *(const u16x8*)(projb + ((size_t)b*T_+t)*H_ + lane*8);
    float acc = 0.f;
#pragma unroll
    for (int j=0;j<8;j++) acc += wv[j]*tanhf(bf2f(vv[j]) + pv[j]);
#pragma unroll
    for (int o=32;o>0;o>>=1) acc += __shfl_down(acc,o);
    if (lane==0) s_e[t] = acc;
  }
  __syncthreads();
  float v = (tid < T_) ? s_e[tid] : -INFINITY;
  float m = v;
#pragma unroll
  for (int o=32;o>0;o>>=1) m = fmaxf(m, __shfl_down(m,o));
  if (lane==0) s_red[wave] = m;
  __syncthreads();
  m = fmaxf(fmaxf(s_red[0],s_red[1]), fmaxf(s_red[2],s_red[3]));
  float p = (tid < T_) ? expf(v - m) : 0.f;
  float sum = p;
#pragma unroll
  for (int o=32;o>0;o>>=1) sum += __shfl_down(sum,o);
  if (lane==0) s_red[4+wave] = sum;
  __syncthreads();
  const float denom = s_red[4]+s_red[5]+s_red[6]+s_red[7];
  if (tid < T_) s_e[tid] = p/denom;
  __syncthreads();
  // context: wave w covers t in [32w, 32w+32), lane covers d = lane*8..+7
  const int d0 = lane*8;
  float a[8] = {0,0,0,0,0,0,0,0};
  for (int t=wave*32; t<wave*32+32; ++t){
    const float al = s_e[t];
    const float* hr = bH + ((size_t)b*T_+t)*D_ + d0;
    float4 h0=*(const float4*)hr, h1=*(const float4*)(hr+4);
    a[0]+=al*h0.x; a[1]+=al*h0.y; a[2]+=al*h0.z; a[3]+=al*h0.w;
    a[4]+=al*h1.x; a[5]+=al*h1.y; a[6]+=al*h1.z; a[7]+=al*h1.w;
  }
  *(float4*)&s_part[wave][d0]   = make_float4(a[0],a[1],a[2],a[3]);
  *(float4*)&s_part[wave][d0+4] = make_float4(a[4],a[5],a[6],a[7]);
  __syncthreads();
  const int d = tid*2;
  float v0 = s_part[0][d]  +s_part[1][d]  +s_part[2][d]  +s_part[3][d];
  float v1 = s_part[0][d+1]+s_part[1][d+1]+s_part[2][d+1]+s_part[3][d+1];
  u16 h0=f2bf_rn(v0), l0=f2bf_rn(v0-bf2f(h0));
  u16 h1=f2bf_rn(v1), l1=f2bf_rn(v1-bf2f(h1));
  ushort2 hh; hh.x=h0; hh.y=h1;
  ushort2 ll; ll.x=l0; ll.y=l1;
  *(ushort2*)&Acat_hi[(size_t)b*1024 + d] = hh;
  *(ushort2*)&Acat_lo[(size_t)b*1024 + d] = ll;
}

// ---------------------------------------------------------------------------
// Fused gates GEMM + LSTM pointwise.
// gates = [ctx|h] @ [W_ih[:,:512] | W_hh]^T  (K=1024, bf16x2 3-pass MFMA)
// B-tile row n = f*16 + jj  ->  Bcat row f*512 + (j0+jj): fragment f holds
// gate f, so each lane owns i,f,g,o of (b, j) in-register for the epilogue.
// Epilogue: + (b_ih+b_hh) + token-column adds, activations, c/h update,
// writes h into Acat cols 512.. and hid planes.
// ---------------------------------------------------------------------------
__global__ __launch_bounds__(256) void gates_lstm(
    const u16* __restrict__ Ah, const u16* __restrict__ Al,     // [512][1024]
    const u16* __restrict__ Bh, const u16* __restrict__ Bl,     // [2048][1024]
    const float* __restrict__ bcomb2,
    const float* __restrict__ WmT, const float* __restrict__ WbT,
    const int* __restrict__ midtok, const int* __restrict__ bottok,
    float* __restrict__ c, float* __restrict__ hf,
    u16* __restrict__ Acat_hi, u16* __restrict__ Acat_lo,
    u16* __restrict__ hid_hi, u16* __restrict__ hid_lo, int s)
{
  constexpr int STR = 40;
  __shared__ short As[64*STR];
  __shared__ short Bs[64*STR];
  const int tid=threadIdx.x, lane=tid&63, w=tid>>6;
  const int j0 = blockIdx.x*16, bm = blockIdx.y*64;

  f32x4v acc[4];
#pragma unroll
  for (int f=0;f<4;f++) acc[f] = (f32x4v){0.f,0.f,0.f,0.f};

  u16x8 ra, rb;
  auto load = [&](int it){
    const int pass = it>>5, kk = (it&31)<<5;
    const u16* Ap = (pass==2)?Al:Ah;
    const u16* Bp = (pass==1)?Bl:Bh;
    {
      int row=tid>>2, cc=(tid&3)*8;
      ra = *(const u16x8*)&Ap[(size_t)(bm+row)*1024 + kk + cc];
      int n=row, brow=(n>>4)*512 + j0 + (n&15);
      rb = *(const u16x8*)&Bp[(size_t)brow*1024 + kk + cc];
    }
  };
  load(0);

  for (int it=0; it<96; ++it){
    __syncthreads();
    { int row=tid>>2, cc=(tid&3)*8;
      *(u16x8*)&As[row*STR+cc] = ra;
      *(u16x8*)&Bs[row*STR+cc] = rb; }
    if (it+1 < 96) load(it+1);
    __syncthreads();
    const int koff = (lane>>4)*8, mrow = lane&15;
    bf16x8v af = *(const bf16x8v*)&As[(w*16+mrow)*STR + koff];
    bf16x8v bfr[4];
#pragma unroll
    for (int f=0;f<4;f++) bfr[f] = *(const bf16x8v*)&Bs[(f*16+mrow)*STR + koff];
#pragma unroll
    for (int f=0;f<4;f++)
      acc[f] = __builtin_amdgcn_mfma_f32_16x16x32_bf16(af, bfr[f], acc[f], 0,0,0);
  }

  // epilogue: lane holds gates f=0..3 for rows r0..r0+3 (b), col jj
  const int r0=(lane>>4)*4, jj=lane&15, j=j0+jj;
#pragma unroll
  for (int r=0;r<4;r++){
    const int b = bm + w*16 + r0 + r;
    const int mt = midtok[b*26 + s];
    const int bt = bottok[b*26 + s];
    const float* wm = WmT + (size_t)mt*2048;
    const float* wb = WbT + (size_t)bt*2048;
    float ig = acc[0][r] + bcomb2[j       ] + wm[j       ] + wb[j       ];
    float fg = acc[1][r] + bcomb2[512 + j ] + wm[512 + j ] + wb[512 + j ];
    float gg = acc[2][r] + bcomb2[1024 + j] + wm[1024 + j] + wb[1024 + j];
    float og = acc[3][r] + bcomb2[1536 + j] + wm[1536 + j] + wb[1536 + j];
    ig = sigmoidf_(ig);
    fg = sigmoidf_(fg);
    gg = tanhf(gg);
    og = sigmoidf_(og);
    const size_t ci = (size_t)b*512 + j;
    const float cn = fg*c[ci] + ig*gg;
    const float hn = og*tanhf(cn);
    c[ci] = cn;
    hf[ci] = hn;
    u16 hh = f2bf_rn(hn), hl = f2bf_rn(hn - bf2f(hh));
    Acat_hi[(size_t)b*1024 + 512 + j] = hh;
    Acat_lo[(size_t)b*1024 + 512 + j] = hl;
    hid_hi[((size_t)s*512 + b)*512 + j] = hh;
    hid_lo[((size_t)s*512 + b)*512 + j] = hl;
  }
}

extern "C" void kernel_launch(void* const* d_in, const int* in_sizes, int n_in,
                              void* d_out, int out_size, void* d_ws, size_t ws_size,
                              hipStream_t stream) {
  const float* bH   = (const float*)d_in[0];
  const int*   midt = (const int*)  d_in[1];
  const int*   bott = (const int*)  d_in[2];
  const float* Wi2h = (const float*)d_in[3];
  const float* Wh2h = (const float*)d_in[4];
  const float* bh2h = (const float*)d_in[5];
  const float* Wsc  = (const float*)d_in[6];
  const float* Wih  = (const float*)d_in[7];
  const float* Whh  = (const float*)d_in[8];
  const float* bih  = (const float*)d_in[9];
  const float* bhh  = (const float*)d_in[10];
  const float* Wgen = (const float*)d_in[11];
  const float* bgen = (const float*)d_in[12];
  float* out = (float*)d_out;

  char* wp = (char*)d_ws;
  u16* projb   = (u16*)wp; wp += (size_t)B_*T_*H_*2;      // 67.1 MB
  u16* bHb     = (u16*)wp; wp += (size_t)B_*T_*D_*2;      // 67.1 MB
  u16* Bcat_hi = (u16*)wp; wp += (size_t)2048*1024*2;     // 4.2 MB
  u16* Bcat_lo = (u16*)wp; wp += (size_t)2048*1024*2;
  u16* Wi2h_h  = (u16*)wp; wp += (size_t)512*512*2;
  u16* Wg_hi   = (u16*)wp; wp += (size_t)64*512*2;
  u16* Wg_lo   = (u16*)wp; wp += (size_t)64*512*2;
  u16* Acat_hi = (u16*)wp; wp += (size_t)B_*1024*2;       // 1 MB
  u16* Acat_lo = (u16*)wp; wp += (size_t)B_*1024*2;
  u16* hid_hi  = (u16*)wp; wp += (size_t)S_*B_*H_*2;      // 13.6 MB
  u16* hid_lo  = (u16*)wp; wp += (size_t)S_*B_*H_*2;
  float* hf    = (float*)wp; wp += (size_t)B_*H_*4;
  float* c     = (float*)wp; wp += (size_t)B_*H_*4;
  float* bcomb2= (float*)wp; wp += (size_t)2048*4;
  float* WmT   = (float*)wp; wp += (size_t)MID_*2048*4;
  float* WbT   = (float*)wp; wp += (size_t)BOT_*2048*4;
  float* Wh2hT = (float*)wp; wp += (size_t)512*512*4;     // 1 MB
  if ((size_t)(wp - (char*)d_ws) > ws_size) return;  // fail loudly

  hipMemsetAsync(Acat_hi, 0, (size_t)B_*1024*2, stream);
  hipMemsetAsync(Acat_lo, 0, (size_t)B_*1024*2, stream);
  hipMemsetAsync(hf, 0, (size_t)B_*H_*4, stream);
  hipMemsetAsync(c,  0, (size_t)B_*H_*4, stream);

  bcomb_kernel<<<8, 256, 0, stream>>>(bih, bhh, bcomb2);
  build_tokT<<<(MID_*2048+255)/256, 256, 0, stream>>>(Wih, WmT, WbT);
  transpose512<<<dim3(16,16), 256, 0, stream>>>(Wh2h, Wh2hT);
  cvt_plane<<<2048, 256, 0, stream>>>(bH, 512, B_*T_, B_*T_, 512, bHb, nullptr);
  cvt_plane<<<64,   256, 0, stream>>>(Wi2h, 512, 512, 512, 512, Wi2h_h, nullptr);
  cvt_plane<<<256,  256, 0, stream>>>(Wih, XL_, 2048, 2048, 1024, Bcat_hi, Bcat_lo);
  cvt_plane<<<256,  256, 0, stream>>>(Whh, 512, 2048, 2048, 1024, Bcat_hi+512, Bcat_lo+512);
  cvt_plane<<<16,   256, 0, stream>>>(Wgen, 512, MID_, 64, 512, Wg_hi, Wg_lo);

  // proj = bf16( batch_H @ W_i2h^T ), 1-pass bf16: M=65536, N=512
  gemm_bf<128,128,1><<<dim3(4,512), 256, 32768, stream>>>(
      bHb,nullptr,512, Wi2h_h,nullptr,512,
      projb,nullptr,512, nullptr, 1, 16);

  for (int s=0; s<S_; ++s){
    attn_kernel<<<B_, 256, 0, stream>>>(
        projb, hf, Wh2hT, bh2h, Wsc, bH, Acat_hi, Acat_lo);
    gates_lstm<<<dim3(32,8), 256, 0, stream>>>(
        Acat_hi, Acat_lo, Bcat_hi, Bcat_lo, bcomb2, WmT, WbT,
        midt, bott, c, hf, Acat_hi, Acat_lo,
        hid_hi, hid_lo, s);
  }

  // out = hid @ W_gen^T + b_gen  (bf16x2), M = S*B = 13312, N=64 (n<38 kept)
  gemm_bf<64,64,2><<<dim3(1,208), 256, 10240, stream>>>(
      hid_hi,hid_lo,512, Wg_hi,Wg_lo,512,
      nullptr,out,0, bgen, 3, 16);
}

// Round 5
// 2452.022 us; speedup vs baseline: 1.4389x; 1.4389x over previous
//
#include <hip/hip_runtime.h>
#include <hip/hip_bf16.h>
#include <hip/hip_fp16.h>
#include <cstdint>
#include <cstddef>

#define B_   512
#define T_   128
#define D_   512
#define H_   512
#define MID_ 38
#define BOT_ 38
#define S_   26
#define XL_  588   // D + MID + BOT = W_ih row length

typedef unsigned short u16;
typedef __attribute__((ext_vector_type(8))) short bf16x8v;
typedef __attribute__((ext_vector_type(8))) unsigned short u16x8;
typedef __attribute__((ext_vector_type(4))) float f32x4v;

__device__ __forceinline__ float sigmoidf_(float x){ return 1.0f/(1.0f+expf(-x)); }
__device__ __forceinline__ u16 f2bf_rn(float f){
  unsigned u = __float_as_uint(f);
  return (u16)((u + 0x7fffu + ((u>>16)&1u)) >> 16);
}
__device__ __forceinline__ float bf2f(u16 v){ return __uint_as_float(((unsigned)v)<<16); }
__device__ __forceinline__ u16 f2h_u(float f){ return __half_as_ushort(__float2half(f)); }
__device__ __forceinline__ float h2f_u(u16 u){ return __half2float(__ushort_as_half(u)); }

// ---------------------------------------------------------------------------
// fp32 -> 16-bit plane decomposition, 512-col chunks, dest ld dld.
// mode 0: hi=bf16, lo=bf16 residual.  mode 1: hi=bf16 only.
// mode 2: hi=bf16, lo=fp16(full value).
// rows >= `rows` zero-padded up to padrows.
// ---------------------------------------------------------------------------
__global__ __launch_bounds__(256) void cvt_plane(
    const float* __restrict__ src, int ld, int rows, int padrows, int dld,
    u16* __restrict__ hi, u16* __restrict__ lo, int mode)
{
  const int n4 = padrows*128;
  for (int i = blockIdx.x*256 + threadIdx.x; i < n4; i += gridDim.x*256){
    const int row = i >> 7, c4 = (i & 127)*4;
    float4 v = make_float4(0.f,0.f,0.f,0.f);
    if (row < rows) v = *(const float4*)&src[(size_t)row*ld + c4];
    ushort4 h;
    h.x=f2bf_rn(v.x); h.y=f2bf_rn(v.y); h.z=f2bf_rn(v.z); h.w=f2bf_rn(v.w);
    *(ushort4*)&hi[(size_t)row*dld + c4] = h;
    if (mode == 0){
      ushort4 l;
      l.x=f2bf_rn(v.x-bf2f(h.x)); l.y=f2bf_rn(v.y-bf2f(h.y));
      l.z=f2bf_rn(v.z-bf2f(h.z)); l.w=f2bf_rn(v.w-bf2f(h.w));
      *(ushort4*)&lo[(size_t)row*dld + c4] = l;
    } else if (mode == 2){
      ushort4 l;
      l.x=f2h_u(v.x); l.y=f2h_u(v.y); l.z=f2h_u(v.z); l.w=f2h_u(v.w);
      *(ushort4*)&lo[(size_t)row*dld + c4] = l;
    }
  }
}

// token-column tables, transposed for coalesced epilogue reads
__global__ __launch_bounds__(256) void build_tokT(
    const float* __restrict__ Wih, float* __restrict__ WmT, float* __restrict__ WbT)
{
  int i = blockIdx.x*256 + threadIdx.x;   // over 38*2048
  if (i < MID_*2048){
    int c = i >> 11, j = i & 2047;
    WmT[i] = Wih[(size_t)j*XL_ + 512 + c];
    WbT[i] = Wih[(size_t)j*XL_ + 512 + MID_ + c];
  }
}

// bcomb2[j] = b_ih[j] + b_hh[j]
__global__ __launch_bounds__(256) void bcomb_kernel(
    const float* __restrict__ bih, const float* __restrict__ bhh,
    float* __restrict__ o)
{
  int i = blockIdx.x*256 + threadIdx.x;
  if (i < 2048) o[i] = bih[i] + bhh[i];
}

// W_h2h [j][k] fp32 -> WTb [k][j] bf16
__global__ __launch_bounds__(256) void transpose_cvt(
    const float* __restrict__ W, u16* __restrict__ WTb)
{
  __shared__ float t[32][33];
  const int bx = blockIdx.x*32, by = blockIdx.y*32;
  const int x = threadIdx.x & 31, y = threadIdx.x >> 5;   // 32 x 8
  for (int yy=y; yy<32; yy+=8) t[yy][x] = W[(size_t)(by+yy)*512 + bx+x];
  __syncthreads();
  for (int yy=y; yy<32; yy+=8) WTb[(size_t)(bx+yy)*512 + by+x] = f2bf_rn(t[x][yy]);
}

// ---------------------------------------------------------------------------
// Pure-bf16 MFMA GEMM (proj and generator), K = kSteps*32, NT.
// npass=1: hi*hi.  npass=3: bf16x2 (hi*hi + hi*lo + lo*hi).
// MODE 1: bf16 out via LDS bounce.  MODE 2: generator out (m->(s,b), n<38,
// +bias2).
// ---------------------------------------------------------------------------
template<int BM,int BN,int MODE>
__global__ __launch_bounds__(256) void gemm_bf(
    const u16* __restrict__ Ah, const u16* __restrict__ Al, int lda,
    const u16* __restrict__ Bh, const u16* __restrict__ Bl, int ldb,
    u16* __restrict__ CoutB, float* __restrict__ Cout, int ldc,
    const float* __restrict__ bias2, int npass, int kSteps)
{
  extern __shared__ char smem[];
  constexpr int STR = 40;                    // padded LDS stride (shorts)
  short* As = (short*)smem;                  // [BM][STR]
  short* Bs = As + BM*STR;                   // [BN][STR]
  const int tid=threadIdx.x, bm=blockIdx.y*BM, bn=blockIdx.x*BN;
  const int w=tid>>6, lane=tid&63, wr=w>>1, wc=w&1;
  constexpr int WM=BM/2, WN=BN/2, FM=WM/16, FN=WN/16;
  constexpr int LA=BM/64, LB=BN/64;          // 16B chunks per thread
  const int nIter = npass*kSteps;

  f32x4v acc[FM][FN];
#pragma unroll
  for (int i=0;i<FM;i++)
#pragma unroll
    for (int j=0;j<FN;j++) acc[i][j] = (f32x4v){0.f,0.f,0.f,0.f};

  u16x8 ra[LA], rb[LB];
  auto load = [&](int it){
    const int pass = it/kSteps, kk = (it%kSteps)<<5;
    const u16* Ap = (pass==2)?Al:Ah;
    const u16* Bp = (pass==1)?Bl:Bh;
#pragma unroll
    for (int L=0; L<LA; L++){
      int t=L*256+tid, row=t>>2, c=(t&3)*8;
      ra[L] = *(const u16x8*)&Ap[(size_t)(bm+row)*lda + kk + c];
    }
#pragma unroll
    for (int L=0; L<LB; L++){
      int t=L*256+tid, row=t>>2, c=(t&3)*8;
      rb[L] = *(const u16x8*)&Bp[(size_t)(bn+row)*ldb + kk + c];
    }
  };
  load(0);

  for (int it=0; it<nIter; ++it){
    __syncthreads();
#pragma unroll
    for (int L=0; L<LA; L++){ int t=L*256+tid; *(u16x8*)&As[(t>>2)*STR+(t&3)*8] = ra[L]; }
#pragma unroll
    for (int L=0; L<LB; L++){ int t=L*256+tid; *(u16x8*)&Bs[(t>>2)*STR+(t&3)*8] = rb[L]; }
    if (it+1 < nIter) load(it+1);
    __syncthreads();
    bf16x8v af[FM], bfr[FN];
    const int koff = (lane>>4)*8, mrow = lane&15;
#pragma unroll
    for (int i=0;i<FM;i++) af[i]  = *(const bf16x8v*)&As[(wr*WM+i*16+mrow)*STR + koff];
#pragma unroll
    for (int j=0;j<FN;j++) bfr[j] = *(const bf16x8v*)&Bs[(wc*WN+j*16+mrow)*STR + koff];
#pragma unroll
    for (int i=0;i<FM;i++)
#pragma unroll
      for (int j=0;j<FN;j++)
        acc[i][j] = __builtin_amdgcn_mfma_f32_16x16x32_bf16(af[i], bfr[j], acc[i][j], 0,0,0);
  }

  // C/D layout (m89): col = lane&15, row = (lane>>4)*4 + r.
  const int r0 = (lane>>4)*4, cn = lane&15;
  if constexpr (MODE==1){
    __syncthreads();
    u16* Ts = (u16*)smem;   // [BM][BN] bf16 bounce
#pragma unroll
    for (int i=0;i<FM;i++)
#pragma unroll
      for (int j=0;j<FN;j++)
#pragma unroll
        for (int r=0;r<4;r++)
          Ts[(wr*WM+i*16+r0+r)*BN + wc*WN+j*16+cn] = f2bf_rn(acc[i][j][r]);
    __syncthreads();
#pragma unroll
    for (int q=0;q<(BM*BN/8)/256;q++){
      int idx = q*256 + tid;
      int row = idx/(BN/8), c8 = (idx%(BN/8))*8;
      *(float4*)&CoutB[(size_t)(bm+row)*ldc + bn + c8] = *(const float4*)&Ts[row*BN + c8];
    }
  } else {
#pragma unroll
    for (int i=0;i<FM;i++)
#pragma unroll
      for (int j=0;j<FN;j++)
#pragma unroll
        for (int r=0;r<4;r++){
          int m = bm + wr*WM + i*16 + r0 + r;       // m = s*512 + b
          int n = bn + wc*WN + j*16 + cn;
          if (n < MID_){
            int s = m >> 9, b = m & 511;
            Cout[((size_t)b*S_ + s)*MID_ + n] = acc[i][j][r] + bias2[n];
          }
        }
  }
}

// ---------------------------------------------------------------------------
// Fused attention, 512 threads (8 waves):
//   pp[j] = h[b,:] . W_h2hT_bf16[:,j] + b_h2h[j]      (k-split GEMV)
//   e[t]  = sum_h Ws[h]*tanh(projb[b,t,h]+pp[h]); softmax over t;
//   ctx[b,d] = sum_t alpha[t]*bHh_fp16[b,t,d] -> Acat hi/lo cols 0..511.
// ---------------------------------------------------------------------------
__global__ __launch_bounds__(512) void attn_kernel(
    const u16* __restrict__ projb, const float* __restrict__ hf,
    const u16* __restrict__ WTb, const float* __restrict__ bh2h,
    const float* __restrict__ Wscore, const u16* __restrict__ bHh,
    u16* __restrict__ Acat_hi, u16* __restrict__ Acat_lo)
{
  __shared__ float s_h[H_];
  __shared__ float s_ppp[4][H_];
  __shared__ float s_pp[H_];
  __shared__ float s_e[T_];
  __shared__ float s_red[16];
  __shared__ float s_part[8][D_];
  const int tid=threadIdx.x, b=blockIdx.x, wave=tid>>6, lane=tid&63;

  s_h[tid] = hf[(size_t)b*H_ + tid];
  __syncthreads();

  // pp GEMV: quarter q handles k in [128q,128q+128); j-group j0 = 4*(tid&127)
  {
    const int q = tid>>7, j0 = (tid&127)*4;
    const int k0 = q*128;
    float a0=0.f,a1=0.f,a2=0.f,a3=0.f;
#pragma unroll 8
    for (int k=k0;k<k0+128;k++){
      const float hk = s_h[k];
      ushort4 w4 = *(const ushort4*)&WTb[(size_t)k*512 + j0];
      a0 += hk*bf2f(w4.x); a1 += hk*bf2f(w4.y);
      a2 += hk*bf2f(w4.z); a3 += hk*bf2f(w4.w);
    }
    s_ppp[q][j0]=a0; s_ppp[q][j0+1]=a1; s_ppp[q][j0+2]=a2; s_ppp[q][j0+3]=a3;
  }
  __syncthreads();
  s_pp[tid] = bh2h[tid] + s_ppp[0][tid]+s_ppp[1][tid]+s_ppp[2][tid]+s_ppp[3][tid];
  __syncthreads();

  float pv[8], wv[8];
  {
    float4 p0=*(const float4*)&s_pp[lane*8], p1=*(const float4*)&s_pp[lane*8+4];
    float4 w0=*(const float4*)&Wscore[lane*8], w1=*(const float4*)&Wscore[lane*8+4];
    pv[0]=p0.x;pv[1]=p0.y;pv[2]=p0.z;pv[3]=p0.w;pv[4]=p1.x;pv[5]=p1.y;pv[6]=p1.z;pv[7]=p1.w;
    wv[0]=w0.x;wv[1]=w0.y;wv[2]=w0.z;wv[3]=w0.w;wv[4]=w1.x;wv[5]=w1.y;wv[6]=w1.z;wv[7]=w1.w;
  }
  // e-phase: wave w handles t = w, w+8, ... (16 rows)
  for (int t=wave; t<T_; t+=8){
    u16x8 vv = *(const u16x8*)(projb + ((size_t)b*T_+t)*H_ + lane*8);
    float acc = 0.f;
#pragma unroll
    for (int j=0;j<8;j++) acc += wv[j]*tanhf(bf2f(vv[j]) + pv[j]);
#pragma unroll
    for (int o=32;o>0;o>>=1) acc += __shfl_down(acc,o);
    if (lane==0) s_e[t] = acc;
  }
  __syncthreads();
  // softmax over s_e[0..127] (threads >=128 idle-participate)
  float v = (tid < T_) ? s_e[tid] : -INFINITY;
  float m = v;
#pragma unroll
  for (int o=32;o>0;o>>=1) m = fmaxf(m, __shfl_down(m,o));
  if (lane==0) s_red[wave] = m;
  __syncthreads();
  m = s_red[0];
#pragma unroll
  for (int q=1;q<8;q++) m = fmaxf(m, s_red[q]);
  float p = (tid < T_) ? expf(v - m) : 0.f;
  float sum = p;
#pragma unroll
  for (int o=32;o>0;o>>=1) sum += __shfl_down(sum,o);
  if (lane==0) s_red[8+wave] = sum;
  __syncthreads();
  float denom = s_red[8];
#pragma unroll
  for (int q=1;q<8;q++) denom += s_red[8+q];
  if (tid < T_) s_e[tid] = p/denom;
  __syncthreads();

  // context: wave w covers t in [16w,16w+16); lane covers d = lane*8..+7
  const int d0 = lane*8;
  float a[8] = {0,0,0,0,0,0,0,0};
  for (int t=wave*16; t<wave*16+16; ++t){
    const float al = s_e[t];
    u16x8 hv = *(const u16x8*)&bHh[((size_t)b*T_+t)*D_ + d0];
#pragma unroll
    for (int j=0;j<8;j++) a[j] += al*h2f_u(hv[j]);
  }
  *(float4*)&s_part[wave][d0]   = make_float4(a[0],a[1],a[2],a[3]);
  *(float4*)&s_part[wave][d0+4] = make_float4(a[4],a[5],a[6],a[7]);
  __syncthreads();
  // reduce across 8 waves; thread owns d = tid
  float vv = s_part[0][tid];
#pragma unroll
  for (int q=1;q<8;q++) vv += s_part[q][tid];
  u16 hh=f2bf_rn(vv), ll=f2bf_rn(vv-bf2f(hh));
  Acat_hi[(size_t)b*1024 + tid] = hh;
  Acat_lo[(size_t)b*1024 + tid] = ll;
}

// ---------------------------------------------------------------------------
// Fused gates GEMM + LSTM pointwise (unchanged from R4).
// gates = [ctx|h] @ [W_ih[:,:512] | W_hh]^T  (K=1024, bf16x2 3-pass MFMA)
// fragment f holds gate f; epilogue does biases + token adds + LSTM update.
// ---------------------------------------------------------------------------
__global__ __launch_bounds__(256) void gates_lstm(
    const u16* __restrict__ Ah, const u16* __restrict__ Al,     // [512][1024]
    const u16* __restrict__ Bh, const u16* __restrict__ Bl,     // [2048][1024]
    const float* __restrict__ bcomb2,
    const float* __restrict__ WmT, const float* __restrict__ WbT,
    const int* __restrict__ midtok, const int* __restrict__ bottok,
    float* __restrict__ c, float* __restrict__ hf,
    u16* __restrict__ Acat_hi, u16* __restrict__ Acat_lo,
    u16* __restrict__ hid_hi, u16* __restrict__ hid_lo, int s)
{
  constexpr int STR = 40;
  __shared__ short As[64*STR];
  __shared__ short Bs[64*STR];
  const int tid=threadIdx.x, lane=tid&63, w=tid>>6;
  const int j0 = blockIdx.x*16, bm = blockIdx.y*64;

  f32x4v acc[4];
#pragma unroll
  for (int f=0;f<4;f++) acc[f] = (f32x4v){0.f,0.f,0.f,0.f};

  u16x8 ra, rb;
  auto load = [&](int it){
    const int pass = it>>5, kk = (it&31)<<5;
    const u16* Ap = (pass==2)?Al:Ah;
    const u16* Bp = (pass==1)?Bl:Bh;
    {
      int row=tid>>2, cc=(tid&3)*8;
      ra = *(const u16x8*)&Ap[(size_t)(bm+row)*1024 + kk + cc];
      int n=row, brow=(n>>4)*512 + j0 + (n&15);
      rb = *(const u16x8*)&Bp[(size_t)brow*1024 + kk + cc];
    }
  };
  load(0);

  for (int it=0; it<96; ++it){
    __syncthreads();
    { int row=tid>>2, cc=(tid&3)*8;
      *(u16x8*)&As[row*STR+cc] = ra;
      *(u16x8*)&Bs[row*STR+cc] = rb; }
    if (it+1 < 96) load(it+1);
    __syncthreads();
    const int koff = (lane>>4)*8, mrow = lane&15;
    bf16x8v af = *(const bf16x8v*)&As[(w*16+mrow)*STR + koff];
    bf16x8v bfr[4];
#pragma unroll
    for (int f=0;f<4;f++) bfr[f] = *(const bf16x8v*)&Bs[(f*16+mrow)*STR + koff];
#pragma unroll
    for (int f=0;f<4;f++)
      acc[f] = __builtin_amdgcn_mfma_f32_16x16x32_bf16(af, bfr[f], acc[f], 0,0,0);
  }

  const int r0=(lane>>4)*4, jj=lane&15, j=j0+jj;
#pragma unroll
  for (int r=0;r<4;r++){
    const int b = bm + w*16 + r0 + r;
    const int mt = midtok[b*26 + s];
    const int bt = bottok[b*26 + s];
    const float* wm = WmT + (size_t)mt*2048;
    const float* wb = WbT + (size_t)bt*2048;
    float ig = acc[0][r] + bcomb2[j       ] + wm[j       ] + wb[j       ];
    float fg = acc[1][r] + bcomb2[512 + j ] + wm[512 + j ] + wb[512 + j ];
    float gg = acc[2][r] + bcomb2[1024 + j] + wm[1024 + j] + wb[1024 + j];
    float og = acc[3][r] + bcomb2[1536 + j] + wm[1536 + j] + wb[1536 + j];
    ig = sigmoidf_(ig);
    fg = sigmoidf_(fg);
    gg = tanhf(gg);
    og = sigmoidf_(og);
    const size_t ci = (size_t)b*512 + j;
    const float cn = fg*c[ci] + ig*gg;
    const float hn = og*tanhf(cn);
    c[ci] = cn;
    hf[ci] = hn;
    u16 hh = f2bf_rn(hn), hl = f2bf_rn(hn - bf2f(hh));
    Acat_hi[(size_t)b*1024 + 512 + j] = hh;
    Acat_lo[(size_t)b*1024 + 512 + j] = hl;
    hid_hi[((size_t)s*512 + b)*512 + j] = hh;
    hid_lo[((size_t)s*512 + b)*512 + j] = hl;
  }
}

extern "C" void kernel_launch(void* const* d_in, const int* in_sizes, int n_in,
                              void* d_out, int out_size, void* d_ws, size_t ws_size,
                              hipStream_t stream) {
  const float* bH   = (const float*)d_in[0];
  const int*   midt = (const int*)  d_in[1];
  const int*   bott = (const int*)  d_in[2];
  const float* Wi2h = (const float*)d_in[3];
  const float* Wh2h = (const float*)d_in[4];
  const float* bh2h = (const float*)d_in[5];
  const float* Wsc  = (const float*)d_in[6];
  const float* Wih  = (const float*)d_in[7];
  const float* Whh  = (const float*)d_in[8];
  const float* bih  = (const float*)d_in[9];
  const float* bhh  = (const float*)d_in[10];
  const float* Wgen = (const float*)d_in[11];
  const float* bgen = (const float*)d_in[12];
  float* out = (float*)d_out;

  char* wp = (char*)d_ws;
  u16* projb   = (u16*)wp; wp += (size_t)B_*T_*H_*2;      // 67.1 MB
  u16* bHh     = (u16*)wp; wp += (size_t)B_*T_*D_*2;      // 67.1 MB fp16 (ctx)
  u16* bHb     = (u16*)wp; wp += (size_t)B_*T_*D_*2;      // 67.1 MB bf16 (proj A, dead after)
  u16* Bcat_hi = (u16*)wp; wp += (size_t)2048*1024*2;     // 4.2 MB
  u16* Bcat_lo = (u16*)wp; wp += (size_t)2048*1024*2;
  u16* Wi2h_h  = (u16*)wp; wp += (size_t)512*512*2;
  u16* Wg_hi   = (u16*)wp; wp += (size_t)64*512*2;
  u16* Wg_lo   = (u16*)wp; wp += (size_t)64*512*2;
  u16* WTb     = (u16*)wp; wp += (size_t)512*512*2;       // W_h2hT bf16
  u16* Acat_hi = (u16*)wp; wp += (size_t)B_*1024*2;       // 1 MB
  u16* Acat_lo = (u16*)wp; wp += (size_t)B_*1024*2;
  u16* hid_hi  = (u16*)wp; wp += (size_t)S_*B_*H_*2;      // 13.6 MB
  u16* hid_lo  = (u16*)wp; wp += (size_t)S_*B_*H_*2;
  float* hf    = (float*)wp; wp += (size_t)B_*H_*4;
  float* c     = (float*)wp; wp += (size_t)B_*H_*4;
  float* bcomb2= (float*)wp; wp += (size_t)2048*4;
  float* WmT   = (float*)wp; wp += (size_t)MID_*2048*4;
  float* WbT   = (float*)wp; wp += (size_t)BOT_*2048*4;
  if ((size_t)(wp - (char*)d_ws) > ws_size) return;  // fail loudly

  hipMemsetAsync(Acat_hi, 0, (size_t)B_*1024*2, stream);
  hipMemsetAsync(Acat_lo, 0, (size_t)B_*1024*2, stream);
  hipMemsetAsync(hf, 0, (size_t)B_*H_*4, stream);
  hipMemsetAsync(c,  0, (size_t)B_*H_*4, stream);

  bcomb_kernel<<<8, 256, 0, stream>>>(bih, bhh, bcomb2);
  build_tokT<<<(MID_*2048+255)/256, 256, 0, stream>>>(Wih, WmT, WbT);
  transpose_cvt<<<dim3(16,16), 256, 0, stream>>>(Wh2h, WTb);
  cvt_plane<<<2048, 256, 0, stream>>>(bH, 512, B_*T_, B_*T_, 512, bHb, bHh, 2);
  cvt_plane<<<64,   256, 0, stream>>>(Wi2h, 512, 512, 512, 512, Wi2h_h, nullptr, 1);
  cvt_plane<<<256,  256, 0, stream>>>(Wih, XL_, 2048, 2048, 1024, Bcat_hi, Bcat_lo, 0);
  cvt_plane<<<256,  256, 0, stream>>>(Whh, 512, 2048, 2048, 1024, Bcat_hi+512, Bcat_lo+512, 0);
  cvt_plane<<<16,   256, 0, stream>>>(Wgen, 512, MID_, 64, 512, Wg_hi, Wg_lo, 0);

  // proj = bf16( batch_H @ W_i2h^T ), 1-pass bf16: M=65536, N=512
  gemm_bf<128,128,1><<<dim3(4,512), 256, 32768, stream>>>(
      bHb,nullptr,512, Wi2h_h,nullptr,512,
      projb,nullptr,512, nullptr, 1, 16);

  for (int s=0; s<S_; ++s){
    attn_kernel<<<B_, 512, 0, stream>>>(
        projb, hf, WTb, bh2h, Wsc, bHh, Acat_hi, Acat_lo);
    gates_lstm<<<dim3(32,8), 256, 0, stream>>>(
        Acat_hi, Acat_lo, Bcat_hi, Bcat_lo, bcomb2, WmT, WbT,
        midt, bott, c, hf, Acat_hi, Acat_lo,
        hid_hi, hid_lo, s);
  }

  // out = hid @ W_gen^T + b_gen  (bf16x2), M = S*B = 13312, N=64 (n<38 kept)
  gemm_bf<64,64,2><<<dim3(1,208), 256, 10240, stream>>>(
      hid_hi,hid_lo,512, Wg_hi,Wg_lo,512,
      nullptr,out,0, bgen, 3, 16);
}

// Round 6
// 2067.902 us; speedup vs baseline: 1.7062x; 1.1858x over previous
//
#include <hip/hip_runtime.h>
#include <hip/hip_bf16.h>
#include <hip/hip_fp16.h>
#include <cstdint>
#include <cstddef>

#define B_   512
#define T_   128
#define D_   512
#define H_   512
#define MID_ 38
#define BOT_ 38
#define S_   26
#define XL_  588   // D + MID + BOT = W_ih row length

typedef unsigned short u16;
typedef __attribute__((ext_vector_type(8))) short bf16x8v;
typedef __attribute__((ext_vector_type(8))) _Float16 f16x8v;
typedef __attribute__((ext_vector_type(8))) unsigned short u16x8;
typedef __attribute__((ext_vector_type(4))) float f32x4v;

__device__ __forceinline__ u16 f2bf_rn(float f){
  unsigned u = __float_as_uint(f);
  return (u16)((u + 0x7fffu + ((u>>16)&1u)) >> 16);
}
__device__ __forceinline__ float bf2f(u16 v){ return __uint_as_float(((unsigned)v)<<16); }
__device__ __forceinline__ u16 f2h_u(float f){ return __half_as_ushort(__float2half(f)); }
__device__ __forceinline__ float h2f_u(u16 u){ return __half2float(__ushort_as_half(u)); }

// branch-free fast transcendentals (v_exp_f32 + v_rcp_f32, ~1e-6 rel err,
// correct saturation at +-inf)
__device__ __forceinline__ float fast_tanh(float x){
  return 1.0f - 2.0f*__builtin_amdgcn_rcpf(__expf(2.0f*x) + 1.0f);
}
__device__ __forceinline__ float fast_sig(float x){
  return __builtin_amdgcn_rcpf(1.0f + __expf(-x));
}

// ---------------------------------------------------------------------------
// fp32 -> 16-bit plane conversion, 512-col chunks, dest ld dld.
// mode 0: hi=bf16, lo=bf16 residual.  mode 1: hi=bf16 only.  mode 3: hi=fp16.
// rows >= `rows` zero-padded up to padrows.
// ---------------------------------------------------------------------------
__global__ __launch_bounds__(256) void cvt_plane(
    const float* __restrict__ src, int ld, int rows, int padrows, int dld,
    u16* __restrict__ hi, u16* __restrict__ lo, int mode)
{
  const int n4 = padrows*128;
  for (int i = blockIdx.x*256 + threadIdx.x; i < n4; i += gridDim.x*256){
    const int row = i >> 7, c4 = (i & 127)*4;
    float4 v = make_float4(0.f,0.f,0.f,0.f);
    if (row < rows) v = *(const float4*)&src[(size_t)row*ld + c4];
    ushort4 h;
    if (mode == 3){
      h.x=f2h_u(v.x); h.y=f2h_u(v.y); h.z=f2h_u(v.z); h.w=f2h_u(v.w);
    } else {
      h.x=f2bf_rn(v.x); h.y=f2bf_rn(v.y); h.z=f2bf_rn(v.z); h.w=f2bf_rn(v.w);
    }
    *(ushort4*)&hi[(size_t)row*dld + c4] = h;
    if (mode == 0){
      ushort4 l;
      l.x=f2bf_rn(v.x-bf2f(h.x)); l.y=f2bf_rn(v.y-bf2f(h.y));
      l.z=f2bf_rn(v.z-bf2f(h.z)); l.w=f2bf_rn(v.w-bf2f(h.w));
      *(ushort4*)&lo[(size_t)row*dld + c4] = l;
    }
  }
}

// token-column tables, transposed for coalesced epilogue reads
__global__ __launch_bounds__(256) void build_tokT(
    const float* __restrict__ Wih, float* __restrict__ WmT, float* __restrict__ WbT)
{
  int i = blockIdx.x*256 + threadIdx.x;   // over 38*2048
  if (i < MID_*2048){
    int c = i >> 11, j = i & 2047;
    WmT[i] = Wih[(size_t)j*XL_ + 512 + c];
    WbT[i] = Wih[(size_t)j*XL_ + 512 + MID_ + c];
  }
}

// bcomb2[j] = b_ih[j] + b_hh[j]
__global__ __launch_bounds__(256) void bcomb_kernel(
    const float* __restrict__ bih, const float* __restrict__ bhh,
    float* __restrict__ o)
{
  int i = blockIdx.x*256 + threadIdx.x;
  if (i < 2048) o[i] = bih[i] + bhh[i];
}

// ---------------------------------------------------------------------------
// MFMA GEMM, K = kSteps*32, NT.  DT 0: bf16 frags.  DT 1: fp16 frags.
// npass=1: hi*hi.  npass=3: bf16x2 split (hi*hi + hi*lo + lo*hi).
// MODE 0: fp32 out + col-bias.  MODE 1: 16-bit out via LDS bounce (fp16 when
// DT==1 else bf16).  MODE 2: generator out (m->(s,b), n<38, +bias2).
// ---------------------------------------------------------------------------
template<int BM,int BN,int MODE,int DT>
__global__ __launch_bounds__(256) void gemm_bf(
    const u16* __restrict__ Ah, const u16* __restrict__ Al, int lda,
    const u16* __restrict__ Bh, const u16* __restrict__ Bl, int ldb,
    u16* __restrict__ CoutB, float* __restrict__ Cout, int ldc,
    const float* __restrict__ bias2, int npass, int kSteps)
{
  extern __shared__ char smem[];
  constexpr int STR = 40;                    // padded LDS stride (shorts)
  short* As = (short*)smem;                  // [BM][STR]
  short* Bs = As + BM*STR;                   // [BN][STR]
  const int tid=threadIdx.x, bm=blockIdx.y*BM, bn=blockIdx.x*BN;
  const int w=tid>>6, lane=tid&63, wr=w>>1, wc=w&1;
  constexpr int WM=BM/2, WN=BN/2, FM=WM/16, FN=WN/16;
  constexpr int LA=BM/64, LB=BN/64;          // 16B chunks per thread
  const int nIter = npass*kSteps;

  f32x4v acc[FM][FN];
#pragma unroll
  for (int i=0;i<FM;i++)
#pragma unroll
    for (int j=0;j<FN;j++) acc[i][j] = (f32x4v){0.f,0.f,0.f,0.f};

  u16x8 ra[LA], rb[LB];
  auto load = [&](int it){
    const int pass = it/kSteps, kk = (it%kSteps)<<5;
    const u16* Ap = (pass==2)?Al:Ah;
    const u16* Bp = (pass==1)?Bl:Bh;
#pragma unroll
    for (int L=0; L<LA; L++){
      int t=L*256+tid, row=t>>2, c=(t&3)*8;
      ra[L] = *(const u16x8*)&Ap[(size_t)(bm+row)*lda + kk + c];
    }
#pragma unroll
    for (int L=0; L<LB; L++){
      int t=L*256+tid, row=t>>2, c=(t&3)*8;
      rb[L] = *(const u16x8*)&Bp[(size_t)(bn+row)*ldb + kk + c];
    }
  };
  load(0);

  for (int it=0; it<nIter; ++it){
    __syncthreads();
#pragma unroll
    for (int L=0; L<LA; L++){ int t=L*256+tid; *(u16x8*)&As[(t>>2)*STR+(t&3)*8] = ra[L]; }
#pragma unroll
    for (int L=0; L<LB; L++){ int t=L*256+tid; *(u16x8*)&Bs[(t>>2)*STR+(t&3)*8] = rb[L]; }
    if (it+1 < nIter) load(it+1);
    __syncthreads();
    const int koff = (lane>>4)*8, mrow = lane&15;
#pragma unroll
    for (int i=0;i<FM;i++)
#pragma unroll
      for (int j=0;j<FN;j++){
        if constexpr (DT==0){
          bf16x8v af = *(const bf16x8v*)&As[(wr*WM+i*16+mrow)*STR + koff];
          bf16x8v bf = *(const bf16x8v*)&Bs[(wc*WN+j*16+mrow)*STR + koff];
          acc[i][j] = __builtin_amdgcn_mfma_f32_16x16x32_bf16(af, bf, acc[i][j], 0,0,0);
        } else {
          f16x8v af = *(const f16x8v*)&As[(wr*WM+i*16+mrow)*STR + koff];
          f16x8v bf = *(const f16x8v*)&Bs[(wc*WN+j*16+mrow)*STR + koff];
          acc[i][j] = __builtin_amdgcn_mfma_f32_16x16x32_f16(af, bf, acc[i][j], 0,0,0);
        }
      }
  }

  // C/D layout (m89): col = lane&15, row = (lane>>4)*4 + r.
  const int r0 = (lane>>4)*4, cn = lane&15;
  if constexpr (MODE==1){
    __syncthreads();
    u16* Ts = (u16*)smem;   // [BM][BN] bounce
#pragma unroll
    for (int i=0;i<FM;i++)
#pragma unroll
      for (int j=0;j<FN;j++)
#pragma unroll
        for (int r=0;r<4;r++){
          float v = acc[i][j][r];
          Ts[(wr*WM+i*16+r0+r)*BN + wc*WN+j*16+cn] = (DT==1)? f2h_u(v) : f2bf_rn(v);
        }
    __syncthreads();
#pragma unroll
    for (int q=0;q<(BM*BN/8)/256;q++){
      int idx = q*256 + tid;
      int row = idx/(BN/8), c8 = (idx%(BN/8))*8;
      *(float4*)&CoutB[(size_t)(bm+row)*ldc + bn + c8] = *(const float4*)&Ts[row*BN + c8];
    }
  } else if constexpr (MODE==2){
#pragma unroll
    for (int i=0;i<FM;i++)
#pragma unroll
      for (int j=0;j<FN;j++)
#pragma unroll
        for (int r=0;r<4;r++){
          int m = bm + wr*WM + i*16 + r0 + r;       // m = s*512 + b
          int n = bn + wc*WN + j*16 + cn;
          if (n < MID_){
            int s = m >> 9, b = m & 511;
            Cout[((size_t)b*S_ + s)*MID_ + n] = acc[i][j][r] + bias2[n];
          }
        }
  } else {
#pragma unroll
    for (int i=0;i<FM;i++)
#pragma unroll
      for (int j=0;j<FN;j++)
#pragma unroll
        for (int r=0;r<4;r++){
          int row = bm + wr*WM + i*16 + r0 + r;
          int col = bn + wc*WN + j*16 + cn;
          float v = acc[i][j][r];
          if (bias2) v += bias2[col];
          Cout[(size_t)row*ldc + col] = v;
        }
  }
}

// ---------------------------------------------------------------------------
// Fused attention, 512 threads:
//   pv from precomputed pp[b][j] (fp32, separate MFMA GEMM)
//   e[t] = sum_h Ws[h]*fast_tanh(projh_fp16[b,t,h]+pp[h]); softmax over t;
//   ctx[b,d] = sum_t alpha[t]*bHh_fp16[b,t,d] -> Acat hi/lo cols 0..511.
// ---------------------------------------------------------------------------
__global__ __launch_bounds__(512) void attn_kernel(
    const u16* __restrict__ projh, const float* __restrict__ pp,
    const float* __restrict__ Wscore, const u16* __restrict__ bHh,
    u16* __restrict__ Acat_hi, u16* __restrict__ Acat_lo)
{
  __shared__ float s_e[T_];
  __shared__ float s_red[16];
  __shared__ float s_part[8][D_];
  const int tid=threadIdx.x, b=blockIdx.x, wave=tid>>6, lane=tid&63;

  float pv[8], wv[8];
  {
    const float* pprow = pp + (size_t)b*512;
    float4 p0=*(const float4*)&pprow[lane*8], p1=*(const float4*)&pprow[lane*8+4];
    float4 w0=*(const float4*)&Wscore[lane*8], w1=*(const float4*)&Wscore[lane*8+4];
    pv[0]=p0.x;pv[1]=p0.y;pv[2]=p0.z;pv[3]=p0.w;pv[4]=p1.x;pv[5]=p1.y;pv[6]=p1.z;pv[7]=p1.w;
    wv[0]=w0.x;wv[1]=w0.y;wv[2]=w0.z;wv[3]=w0.w;wv[4]=w1.x;wv[5]=w1.y;wv[6]=w1.z;wv[7]=w1.w;
  }
  // e-phase: wave w handles t = w, w+8, ... (16 rows)
  for (int t=wave; t<T_; t+=8){
    u16x8 vv = *(const u16x8*)(projh + ((size_t)b*T_+t)*H_ + lane*8);
    float acc = 0.f;
#pragma unroll
    for (int j=0;j<8;j++) acc += wv[j]*fast_tanh(h2f_u(vv[j]) + pv[j]);
#pragma unroll
    for (int o=32;o>0;o>>=1) acc += __shfl_down(acc,o);
    if (lane==0) s_e[t] = acc;
  }
  __syncthreads();
  // softmax over s_e[0..127]
  float v = (tid < T_) ? s_e[tid] : -INFINITY;
  float m = v;
#pragma unroll
  for (int o=32;o>0;o>>=1) m = fmaxf(m, __shfl_down(m,o));
  if (lane==0) s_red[wave] = m;
  __syncthreads();
  m = s_red[0];
#pragma unroll
  for (int q=1;q<8;q++) m = fmaxf(m, s_red[q]);
  float p = (tid < T_) ? __expf(v - m) : 0.f;
  float sum = p;
#pragma unroll
  for (int o=32;o>0;o>>=1) sum += __shfl_down(sum,o);
  if (lane==0) s_red[8+wave] = sum;
  __syncthreads();
  float denom = s_red[8];
#pragma unroll
  for (int q=1;q<8;q++) denom += s_red[8+q];
  if (tid < T_) s_e[tid] = p/denom;
  __syncthreads();

  // context: wave w covers t in [16w,16w+16); lane covers d = lane*8..+7
  const int d0 = lane*8;
  float a[8] = {0,0,0,0,0,0,0,0};
  for (int t=wave*16; t<wave*16+16; ++t){
    const float al = s_e[t];
    u16x8 hv = *(const u16x8*)&bHh[((size_t)b*T_+t)*D_ + d0];
#pragma unroll
    for (int j=0;j<8;j++) a[j] += al*h2f_u(hv[j]);
  }
  *(float4*)&s_part[wave][d0]   = make_float4(a[0],a[1],a[2],a[3]);
  *(float4*)&s_part[wave][d0+4] = make_float4(a[4],a[5],a[6],a[7]);
  __syncthreads();
  float vv = s_part[0][tid];
#pragma unroll
  for (int q=1;q<8;q++) vv += s_part[q][tid];
  u16 hh=f2bf_rn(vv), ll=f2bf_rn(vv-bf2f(hh));
  Acat_hi[(size_t)b*1024 + tid] = hh;
  Acat_lo[(size_t)b*1024 + tid] = ll;
}

// ---------------------------------------------------------------------------
// Fused gates GEMM + LSTM pointwise.  K=1024 bf16x2 3-pass, BK=64.
// A fragments loaded direct from global (not wave-shared); B tile via LDS.
// B row n = f*16+jj -> Bcat row f*512+(j0+jj): fragment f holds gate f.
// ---------------------------------------------------------------------------
__global__ __launch_bounds__(256) void gates_lstm(
    const u16* __restrict__ Ah, const u16* __restrict__ Al,     // [512][1024]
    const u16* __restrict__ Bh, const u16* __restrict__ Bl,     // [2048][1024]
    const float* __restrict__ bcomb2,
    const float* __restrict__ WmT, const float* __restrict__ WbT,
    const int* __restrict__ midtok, const int* __restrict__ bottok,
    float* __restrict__ c,
    u16* __restrict__ Acat_hi, u16* __restrict__ Acat_lo,
    u16* __restrict__ hid_hi, u16* __restrict__ hid_lo, int s)
{
  constexpr int STR = 72;                 // 64 + 8 pad (2-way read, free)
  __shared__ short Bs[64*STR];
  const int tid=threadIdx.x, lane=tid&63, w=tid>>6;
  const int j0 = blockIdx.x*16, bm = blockIdx.y*64;
  const int mrow=lane&15, koff=(lane>>4)*8;
  const int arow = bm + w*16 + mrow;
  const int srow = tid>>2, scc=(tid&3)*8;
  const int sbrow = (srow>>4)*512 + j0 + (srow&15);

  f32x4v acc[4];
#pragma unroll
  for (int f=0;f<4;f++) acc[f] = (f32x4v){0.f,0.f,0.f,0.f};

  u16x8 sb0, sb1;
  bf16x8v a0[2], a1[2];
  auto loadB = [&](int it){
    const int pass = it>>4, kk=(it&15)<<6;
    const u16* Bp = (pass==1)?Bl:Bh;
    sb0 = *(const u16x8*)&Bp[(size_t)sbrow*1024 + kk + scc];
    sb1 = *(const u16x8*)&Bp[(size_t)sbrow*1024 + kk + scc + 32];
  };
  auto loadA0 = [&](int it){
    const int pass = it>>4, kk=(it&15)<<6;
    const u16* Ap = (pass==2)?Al:Ah;
    a0[0] = *(const bf16x8v*)&Ap[(size_t)arow*1024 + kk + koff];
    a0[1] = *(const bf16x8v*)&Ap[(size_t)arow*1024 + kk + koff + 32];
  };
  auto loadA1 = [&](int it){
    const int pass = it>>4, kk=(it&15)<<6;
    const u16* Ap = (pass==2)?Al:Ah;
    a1[0] = *(const bf16x8v*)&Ap[(size_t)arow*1024 + kk + koff];
    a1[1] = *(const bf16x8v*)&Ap[(size_t)arow*1024 + kk + koff + 32];
  };

  loadB(0); loadA0(0);
  for (int it=0; it<48; it+=2){
    // --- even iter: consume a0/sb, prefetch it+1 into a1 ---
    __syncthreads();
    *(u16x8*)&Bs[srow*STR+scc]    = sb0;
    *(u16x8*)&Bs[srow*STR+scc+32] = sb1;
    if (it+1 < 48){ loadB(it+1); loadA1(it+1); }
    __syncthreads();
#pragma unroll
    for (int f=0;f<4;f++){
      bf16x8v b0 = *(const bf16x8v*)&Bs[(f*16+mrow)*STR + koff];
      bf16x8v b1 = *(const bf16x8v*)&Bs[(f*16+mrow)*STR + koff + 32];
      acc[f] = __builtin_amdgcn_mfma_f32_16x16x32_bf16(a0[0], b0, acc[f], 0,0,0);
      acc[f] = __builtin_amdgcn_mfma_f32_16x16x32_bf16(a0[1], b1, acc[f], 0,0,0);
    }
    if (it+1 >= 48) break;
    // --- odd iter: consume a1/sb, prefetch it+2 into a0 ---
    __syncthreads();
    *(u16x8*)&Bs[srow*STR+scc]    = sb0;
    *(u16x8*)&Bs[srow*STR+scc+32] = sb1;
    if (it+2 < 48){ loadB(it+2); loadA0(it+2); }
    __syncthreads();
#pragma unroll
    for (int f=0;f<4;f++){
      bf16x8v b0 = *(const bf16x8v*)&Bs[(f*16+mrow)*STR + koff];
      bf16x8v b1 = *(const bf16x8v*)&Bs[(f*16+mrow)*STR + koff + 32];
      acc[f] = __builtin_amdgcn_mfma_f32_16x16x32_bf16(a1[0], b0, acc[f], 0,0,0);
      acc[f] = __builtin_amdgcn_mfma_f32_16x16x32_bf16(a1[1], b1, acc[f], 0,0,0);
    }
  }

  // epilogue: lane holds gates f=0..3 for rows r0..r0+3 (b), col jj
  const int r0=(lane>>4)*4, jj=lane&15, j=j0+jj;
#pragma unroll
  for (int r=0;r<4;r++){
    const int b = bm + w*16 + r0 + r;
    const int mt = midtok[b*26 + s];
    const int bt = bottok[b*26 + s];
    const float* wm = WmT + (size_t)mt*2048;
    const float* wb = WbT + (size_t)bt*2048;
    float ig = acc[0][r] + bcomb2[j       ] + wm[j       ] + wb[j       ];
    float fg = acc[1][r] + bcomb2[512 + j ] + wm[512 + j ] + wb[512 + j ];
    float gg = acc[2][r] + bcomb2[1024 + j] + wm[1024 + j] + wb[1024 + j];
    float og = acc[3][r] + bcomb2[1536 + j] + wm[1536 + j] + wb[1536 + j];
    ig = fast_sig(ig);
    fg = fast_sig(fg);
    gg = fast_tanh(gg);
    og = fast_sig(og);
    const size_t ci = (size_t)b*512 + j;
    const float cn = fg*c[ci] + ig*gg;
    const float hn = og*fast_tanh(cn);
    c[ci] = cn;
    u16 hh = f2bf_rn(hn), hl = f2bf_rn(hn - bf2f(hh));
    Acat_hi[(size_t)b*1024 + 512 + j] = hh;
    Acat_lo[(size_t)b*1024 + 512 + j] = hl;
    hid_hi[((size_t)s*512 + b)*512 + j] = hh;
    hid_lo[((size_t)s*512 + b)*512 + j] = hl;
  }
}

extern "C" void kernel_launch(void* const* d_in, const int* in_sizes, int n_in,
                              void* d_out, int out_size, void* d_ws, size_t ws_size,
                              hipStream_t stream) {
  const float* bH   = (const float*)d_in[0];
  const int*   midt = (const int*)  d_in[1];
  const int*   bott = (const int*)  d_in[2];
  const float* Wi2h = (const float*)d_in[3];
  const float* Wh2h = (const float*)d_in[4];
  const float* bh2h = (const float*)d_in[5];
  const float* Wsc  = (const float*)d_in[6];
  const float* Wih  = (const float*)d_in[7];
  const float* Whh  = (const float*)d_in[8];
  const float* bih  = (const float*)d_in[9];
  const float* bhh  = (const float*)d_in[10];
  const float* Wgen = (const float*)d_in[11];
  const float* bgen = (const float*)d_in[12];
  float* out = (float*)d_out;

  char* wp = (char*)d_ws;
  u16* projh   = (u16*)wp; wp += (size_t)B_*T_*H_*2;      // 67.1 MB fp16
  u16* bHh     = (u16*)wp; wp += (size_t)B_*T_*D_*2;      // 67.1 MB fp16
  u16* Bcat_hi = (u16*)wp; wp += (size_t)2048*1024*2;     // 4.2 MB
  u16* Bcat_lo = (u16*)wp; wp += (size_t)2048*1024*2;
  u16* Wi2h_h  = (u16*)wp; wp += (size_t)512*512*2;       // fp16
  u16* Wh2h_hi = (u16*)wp; wp += (size_t)512*512*2;
  u16* Wh2h_lo = (u16*)wp; wp += (size_t)512*512*2;
  u16* Wg_hi   = (u16*)wp; wp += (size_t)64*512*2;
  u16* Wg_lo   = (u16*)wp; wp += (size_t)64*512*2;
  u16* Acat_hi = (u16*)wp; wp += (size_t)B_*1024*2;       // 1 MB
  u16* Acat_lo = (u16*)wp; wp += (size_t)B_*1024*2;
  u16* hid_hi  = (u16*)wp; wp += (size_t)S_*B_*H_*2;      // 13.6 MB
  u16* hid_lo  = (u16*)wp; wp += (size_t)S_*B_*H_*2;
  float* pp    = (float*)wp; wp += (size_t)B_*512*4;      // 1 MB
  float* c     = (float*)wp; wp += (size_t)B_*H_*4;
  float* bcomb2= (float*)wp; wp += (size_t)2048*4;
  float* WmT   = (float*)wp; wp += (size_t)MID_*2048*4;
  float* WbT   = (float*)wp; wp += (size_t)BOT_*2048*4;
  if ((size_t)(wp - (char*)d_ws) > ws_size) return;  // fail loudly

  hipMemsetAsync(Acat_hi, 0, (size_t)B_*1024*2, stream);
  hipMemsetAsync(Acat_lo, 0, (size_t)B_*1024*2, stream);
  hipMemsetAsync(c, 0, (size_t)B_*H_*4, stream);

  bcomb_kernel<<<8, 256, 0, stream>>>(bih, bhh, bcomb2);
  build_tokT<<<(MID_*2048+255)/256, 256, 0, stream>>>(Wih, WmT, WbT);
  cvt_plane<<<2048, 256, 0, stream>>>(bH, 512, B_*T_, B_*T_, 512, bHh, nullptr, 3);
  cvt_plane<<<64,   256, 0, stream>>>(Wi2h, 512, 512, 512, 512, Wi2h_h, nullptr, 3);
  cvt_plane<<<64,   256, 0, stream>>>(Wh2h, 512, 512, 512, 512, Wh2h_hi, Wh2h_lo, 0);
  cvt_plane<<<256,  256, 0, stream>>>(Wih, XL_, 2048, 2048, 1024, Bcat_hi, Bcat_lo, 0);
  cvt_plane<<<256,  256, 0, stream>>>(Whh, 512, 2048, 2048, 1024, Bcat_hi+512, Bcat_lo+512, 0);
  cvt_plane<<<16,   256, 0, stream>>>(Wgen, 512, MID_, 64, 512, Wg_hi, Wg_lo, 0);

  // proj = fp16( batch_H @ W_i2h^T ), fp16 MFMA 1-pass: M=65536, N=512
  gemm_bf<128,128,1,1><<<dim3(4,512), 256, 32768, stream>>>(
      bHh,nullptr,512, Wi2h_h,nullptr,512,
      projh,nullptr,512, nullptr, 1, 16);

  for (int s=0; s<S_; ++s){
    // pp = h @ W_h2h^T + b_h2h   (bf16x2, A = Acat h-planes)
    gemm_bf<64,64,0,0><<<dim3(8,8), 256, 10240, stream>>>(
        Acat_hi+512, Acat_lo+512, 1024, Wh2h_hi, Wh2h_lo, 512,
        nullptr, pp, 512, bh2h, 3, 16);
    attn_kernel<<<B_, 512, 0, stream>>>(
        projh, pp, Wsc, bHh, Acat_hi, Acat_lo);
    gates_lstm<<<dim3(32,8), 256, 0, stream>>>(
        Acat_hi, Acat_lo, Bcat_hi, Bcat_lo, bcomb2, WmT, WbT,
        midt, bott, c, Acat_hi, Acat_lo,
        hid_hi, hid_lo, s);
  }

  // out = hid @ W_gen^T + b_gen  (bf16x2), M = S*B = 13312, N=64 (n<38 kept)
  gemm_bf<64,64,2,0><<<dim3(1,208), 256, 10240, stream>>>(
      hid_hi,hid_lo,512, Wg_hi,Wg_lo,512,
      nullptr,out,0, bgen, 3, 16);
}

// Round 7
// 1762.209 us; speedup vs baseline: 2.0021x; 1.1735x over previous
//
#include <hip/hip_runtime.h>
#include <hip/hip_bf16.h>
#include <hip/hip_fp16.h>
#include <cstdint>
#include <cstddef>

#define B_   512
#define T_   128
#define D_   512
#define H_   512
#define MID_ 38
#define BOT_ 38
#define S_   26
#define XL_  588   // D + MID + BOT = W_ih row length

typedef unsigned short u16;
typedef __attribute__((ext_vector_type(8))) short bf16x8v;
typedef __attribute__((ext_vector_type(8))) _Float16 f16x8v;
typedef __attribute__((ext_vector_type(8))) unsigned short u16x8;
typedef __attribute__((ext_vector_type(4))) float f32x4v;

__device__ __forceinline__ u16 f2bf_rn(float f){
  unsigned u = __float_as_uint(f);
  return (u16)((u + 0x7fffu + ((u>>16)&1u)) >> 16);
}
__device__ __forceinline__ float bf2f(u16 v){ return __uint_as_float(((unsigned)v)<<16); }
__device__ __forceinline__ u16 f2h_u(float f){ return __half_as_ushort(__float2half(f)); }
__device__ __forceinline__ float h2f_u(u16 u){ return __half2float(__ushort_as_half(u)); }

// branch-free fast transcendentals (v_exp_f32 + v_rcp_f32, ~1e-6 rel err)
__device__ __forceinline__ float fast_tanh(float x){
  return 1.0f - 2.0f*__builtin_amdgcn_rcpf(__expf(2.0f*x) + 1.0f);
}
__device__ __forceinline__ float fast_sig(float x){
  return __builtin_amdgcn_rcpf(1.0f + __expf(-x));
}

// ---------------------------------------------------------------------------
// fp32 -> 16-bit plane conversion, 512-col chunks, dest ld dld.
// mode 0: hi=bf16, lo=bf16 residual.  mode 3: hi=fp16 only.
// rows >= `rows` zero-padded up to padrows.
// ---------------------------------------------------------------------------
__global__ __launch_bounds__(256) void cvt_plane(
    const float* __restrict__ src, int ld, int rows, int padrows, int dld,
    u16* __restrict__ hi, u16* __restrict__ lo, int mode)
{
  const int n4 = padrows*128;
  for (int i = blockIdx.x*256 + threadIdx.x; i < n4; i += gridDim.x*256){
    const int row = i >> 7, c4 = (i & 127)*4;
    float4 v = make_float4(0.f,0.f,0.f,0.f);
    if (row < rows) v = *(const float4*)&src[(size_t)row*ld + c4];
    ushort4 h;
    if (mode == 3){
      h.x=f2h_u(v.x); h.y=f2h_u(v.y); h.z=f2h_u(v.z); h.w=f2h_u(v.w);
    } else {
      h.x=f2bf_rn(v.x); h.y=f2bf_rn(v.y); h.z=f2bf_rn(v.z); h.w=f2bf_rn(v.w);
    }
    *(ushort4*)&hi[(size_t)row*dld + c4] = h;
    if (mode == 0){
      ushort4 l;
      l.x=f2bf_rn(v.x-bf2f(h.x)); l.y=f2bf_rn(v.y-bf2f(h.y));
      l.z=f2bf_rn(v.z-bf2f(h.z)); l.w=f2bf_rn(v.w-bf2f(h.w));
      *(ushort4*)&lo[(size_t)row*dld + c4] = l;
    }
  }
}

// token-column tables, transposed for coalesced epilogue reads
__global__ __launch_bounds__(256) void build_tokT(
    const float* __restrict__ Wih, float* __restrict__ WmT, float* __restrict__ WbT)
{
  int i = blockIdx.x*256 + threadIdx.x;   // over 38*2048
  if (i < MID_*2048){
    int c = i >> 11, j = i & 2047;
    WmT[i] = Wih[(size_t)j*XL_ + 512 + c];
    WbT[i] = Wih[(size_t)j*XL_ + 512 + MID_ + c];
  }
}

// bcombF[0:512] = b_h2h; bcombF[512+j] = b_ih[j] + b_hh[j]
__global__ __launch_bounds__(256) void bcomb_kernel(
    const float* __restrict__ bh2h, const float* __restrict__ bih,
    const float* __restrict__ bhh, float* __restrict__ o)
{
  int i = blockIdx.x*256 + threadIdx.x;
  if (i < 512) o[i] = bh2h[i];
  else if (i < 2560) o[i] = bih[i-512] + bhh[i-512];
}

// ---------------------------------------------------------------------------
// proj GEMM with fused A conversion: A = batch_H fp32 -> fp16 in staging;
// bn==0 blocks side-write the fp16 A tile to bHh.  B = Wi2h fp16.
// C = fp16 projh via LDS bounce.  BM=BN=128, K=512, fp16 MFMA.
// ---------------------------------------------------------------------------
__global__ __launch_bounds__(256) void gemm_proj(
    const float* __restrict__ A, const u16* __restrict__ Bh,
    u16* __restrict__ bHh, u16* __restrict__ projh)
{
  extern __shared__ char smem[];
  constexpr int STR = 40;
  short* As = (short*)smem;                  // [128][STR]
  short* Bs = As + 128*STR;
  const int tid=threadIdx.x, bm=blockIdx.y*128, bn=blockIdx.x*128;
  const int w=tid>>6, lane=tid&63, wr=w>>1, wc=w&1;
  const bool wrA = (blockIdx.x == 0);

  f32x4v acc[4][4];
#pragma unroll
  for (int i=0;i<4;i++)
#pragma unroll
    for (int j=0;j<4;j++) acc[i][j] = (f32x4v){0.f,0.f,0.f,0.f};

  float4 fa[2][2];
  u16x8 rb[2];
  auto load = [&](int it){
    const int kk = it<<5;
#pragma unroll
    for (int L=0; L<2; L++){
      int t=L*256+tid, row=t>>2, c=(t&3)*8;
      const float* p = &A[(size_t)(bm+row)*512 + kk + c];
      fa[L][0] = *(const float4*)p;
      fa[L][1] = *(const float4*)(p+4);
      rb[L] = *(const u16x8*)&Bh[(size_t)(bn+(t>>2))*512 + kk + c];
    }
  };
  load(0);

  for (int it=0; it<16; ++it){
    const int kk = it<<5;
    __syncthreads();
#pragma unroll
    for (int L=0; L<2; L++){
      int t=L*256+tid, row=t>>2, c=(t&3)*8;
      u16x8 hv;
      hv[0]=f2h_u(fa[L][0].x); hv[1]=f2h_u(fa[L][0].y);
      hv[2]=f2h_u(fa[L][0].z); hv[3]=f2h_u(fa[L][0].w);
      hv[4]=f2h_u(fa[L][1].x); hv[5]=f2h_u(fa[L][1].y);
      hv[6]=f2h_u(fa[L][1].z); hv[7]=f2h_u(fa[L][1].w);
      *(u16x8*)&As[row*STR+c] = hv;
      if (wrA) *(u16x8*)&bHh[(size_t)(bm+row)*512 + kk + c] = hv;
      *(u16x8*)&Bs[row*STR+c] = rb[L];
    }
    if (it+1 < 16) load(it+1);
    __syncthreads();
    const int koff = (lane>>4)*8, mrow = lane&15;
#pragma unroll
    for (int i=0;i<4;i++)
#pragma unroll
      for (int j=0;j<4;j++){
        f16x8v af = *(const f16x8v*)&As[(wr*64+i*16+mrow)*STR + koff];
        f16x8v bf = *(const f16x8v*)&Bs[(wc*64+j*16+mrow)*STR + koff];
        acc[i][j] = __builtin_amdgcn_mfma_f32_16x16x32_f16(af, bf, acc[i][j], 0,0,0);
      }
  }

  // epilogue: fp16 out via LDS bounce
  const int r0 = (lane>>4)*4, cn = lane&15;
  __syncthreads();
  u16* Ts = (u16*)smem;   // [128][128]
#pragma unroll
  for (int i=0;i<4;i++)
#pragma unroll
    for (int j=0;j<4;j++)
#pragma unroll
      for (int r=0;r<4;r++)
        Ts[(wr*64+i*16+r0+r)*128 + wc*64+j*16+cn] = f2h_u(acc[i][j][r]);
  __syncthreads();
#pragma unroll
  for (int q=0;q<8;q++){
    int idx = q*256 + tid;
    int row = idx>>4, c8 = (idx&15)*8;
    *(float4*)&projh[(size_t)(bm+row)*512 + bn + c8] = *(const float4*)&Ts[row*128 + c8];
  }
}

// ---------------------------------------------------------------------------
// bf16 MFMA GEMM (hcombo and generator), K = kSteps*32, NT, bf16x2 3-pass.
// MODE 0: fp32 out + col-bias.  MODE 2: generator out (m->(s,b), n<38, +bias2).
// ---------------------------------------------------------------------------
template<int BM,int BN,int MODE>
__global__ __launch_bounds__(256) void gemm_bf(
    const u16* __restrict__ Ah, const u16* __restrict__ Al, int lda,
    const u16* __restrict__ Bh, const u16* __restrict__ Bl, int ldb,
    float* __restrict__ Cout, int ldc,
    const float* __restrict__ bias2, int npass, int kSteps)
{
  extern __shared__ char smem[];
  constexpr int STR = 40;
  short* As = (short*)smem;                  // [BM][STR]
  short* Bs = As + BM*STR;                   // [BN][STR]
  const int tid=threadIdx.x, bm=blockIdx.y*BM, bn=blockIdx.x*BN;
  const int w=tid>>6, lane=tid&63, wr=w>>1, wc=w&1;
  constexpr int WM=BM/2, WN=BN/2, FM=WM/16, FN=WN/16;
  constexpr int LA=BM/64, LB=BN/64;
  const int nIter = npass*kSteps;

  f32x4v acc[FM][FN];
#pragma unroll
  for (int i=0;i<FM;i++)
#pragma unroll
    for (int j=0;j<FN;j++) acc[i][j] = (f32x4v){0.f,0.f,0.f,0.f};

  u16x8 ra[LA], rb[LB];
  auto load = [&](int it){
    const int pass = it/kSteps, kk = (it%kSteps)<<5;
    const u16* Ap = (pass==2)?Al:Ah;
    const u16* Bp = (pass==1)?Bl:Bh;
#pragma unroll
    for (int L=0; L<LA; L++){
      int t=L*256+tid, row=t>>2, c=(t&3)*8;
      ra[L] = *(const u16x8*)&Ap[(size_t)(bm+row)*lda + kk + c];
    }
#pragma unroll
    for (int L=0; L<LB; L++){
      int t=L*256+tid, row=t>>2, c=(t&3)*8;
      rb[L] = *(const u16x8*)&Bp[(size_t)(bn+row)*ldb + kk + c];
    }
  };
  load(0);

  for (int it=0; it<nIter; ++it){
    __syncthreads();
#pragma unroll
    for (int L=0; L<LA; L++){ int t=L*256+tid; *(u16x8*)&As[(t>>2)*STR+(t&3)*8] = ra[L]; }
#pragma unroll
    for (int L=0; L<LB; L++){ int t=L*256+tid; *(u16x8*)&Bs[(t>>2)*STR+(t&3)*8] = rb[L]; }
    if (it+1 < nIter) load(it+1);
    __syncthreads();
    const int koff = (lane>>4)*8, mrow = lane&15;
#pragma unroll
    for (int i=0;i<FM;i++)
#pragma unroll
      for (int j=0;j<FN;j++){
        bf16x8v af = *(const bf16x8v*)&As[(wr*WM+i*16+mrow)*STR + koff];
        bf16x8v bf = *(const bf16x8v*)&Bs[(wc*WN+j*16+mrow)*STR + koff];
        acc[i][j] = __builtin_amdgcn_mfma_f32_16x16x32_bf16(af, bf, acc[i][j], 0,0,0);
      }
  }

  const int r0 = (lane>>4)*4, cn = lane&15;
  if constexpr (MODE==2){
#pragma unroll
    for (int i=0;i<FM;i++)
#pragma unroll
      for (int j=0;j<FN;j++)
#pragma unroll
        for (int r=0;r<4;r++){
          int m = bm + wr*WM + i*16 + r0 + r;       // m = s*512 + b
          int n = bn + wc*WN + j*16 + cn;
          if (n < MID_){
            int s = m >> 9, b = m & 511;
            Cout[((size_t)b*S_ + s)*MID_ + n] = acc[i][j][r] + bias2[n];
          }
        }
  } else {
#pragma unroll
    for (int i=0;i<FM;i++)
#pragma unroll
      for (int j=0;j<FN;j++)
#pragma unroll
        for (int r=0;r<4;r++){
          int row = bm + wr*WM + i*16 + r0 + r;
          int col = bn + wc*WN + j*16 + cn;
          float v = acc[i][j][r];
          if (bias2) v += bias2[col];
          Cout[(size_t)row*ldc + col] = v;
        }
  }
}

// ---------------------------------------------------------------------------
// Fused attention, 512 threads:
//   pp from combo[b][0:512] (fp32, ld 2560)
//   e[t] = sum_h Ws[h]*fast_tanh(projh[b,t,h]+pp[h]); softmax over t;
//   ctx[b,d] = sum_t alpha[t]*bHh[b,t,d] -> ctx hi/lo planes.
// ---------------------------------------------------------------------------
__global__ __launch_bounds__(512) void attn_kernel(
    const u16* __restrict__ projh, const float* __restrict__ combo,
    const float* __restrict__ Wscore, const u16* __restrict__ bHh,
    u16* __restrict__ ctx_hi, u16* __restrict__ ctx_lo)
{
  __shared__ float s_e[T_];
  __shared__ float s_red[16];
  __shared__ float s_part[8][D_];
  const int tid=threadIdx.x, b=blockIdx.x, wave=tid>>6, lane=tid&63;

  float pv[8], wv[8];
  {
    const float* pprow = combo + (size_t)b*2560;
    float4 p0=*(const float4*)&pprow[lane*8], p1=*(const float4*)&pprow[lane*8+4];
    float4 w0=*(const float4*)&Wscore[lane*8], w1=*(const float4*)&Wscore[lane*8+4];
    pv[0]=p0.x;pv[1]=p0.y;pv[2]=p0.z;pv[3]=p0.w;pv[4]=p1.x;pv[5]=p1.y;pv[6]=p1.z;pv[7]=p1.w;
    wv[0]=w0.x;wv[1]=w0.y;wv[2]=w0.z;wv[3]=w0.w;wv[4]=w1.x;wv[5]=w1.y;wv[6]=w1.z;wv[7]=w1.w;
  }
  // e-phase: wave w handles t = w, w+8, ...; 2-deep load pipeline
  {
    const u16* base = projh + (size_t)b*T_*H_ + lane*8;
    u16x8 cur = *(const u16x8*)(base + (size_t)wave*H_);
    for (int t=wave; t<T_; t+=8){
      u16x8 nxt;
      if (t+8 < T_) nxt = *(const u16x8*)(base + (size_t)(t+8)*H_);
      float acc = 0.f;
#pragma unroll
      for (int j=0;j<8;j++) acc += wv[j]*fast_tanh(h2f_u(cur[j]) + pv[j]);
#pragma unroll
      for (int o=32;o>0;o>>=1) acc += __shfl_down(acc,o);
      if (lane==0) s_e[t] = acc;
      cur = nxt;
    }
  }
  __syncthreads();
  // softmax over s_e[0..127]
  float v = (tid < T_) ? s_e[tid] : -INFINITY;
  float m = v;
#pragma unroll
  for (int o=32;o>0;o>>=1) m = fmaxf(m, __shfl_down(m,o));
  if (lane==0) s_red[wave] = m;
  __syncthreads();
  m = s_red[0];
#pragma unroll
  for (int q=1;q<8;q++) m = fmaxf(m, s_red[q]);
  float p = (tid < T_) ? __expf(v - m) : 0.f;
  float sum = p;
#pragma unroll
  for (int o=32;o>0;o>>=1) sum += __shfl_down(sum,o);
  if (lane==0) s_red[8+wave] = sum;
  __syncthreads();
  float denom = s_red[8];
#pragma unroll
  for (int q=1;q<8;q++) denom += s_red[8+q];
  if (tid < T_) s_e[tid] = p/denom;
  __syncthreads();

  // context: wave w covers t in [16w,16w+16); lane covers d = lane*8..+7
  const int d0 = lane*8;
  float a[8] = {0,0,0,0,0,0,0,0};
  {
    const u16* base = bHh + (size_t)b*T_*D_ + d0;
    u16x8 cur = *(const u16x8*)(base + (size_t)(wave*16)*D_);
    for (int t=wave*16; t<wave*16+16; ++t){
      u16x8 nxt;
      if (t+1 < wave*16+16) nxt = *(const u16x8*)(base + (size_t)(t+1)*D_);
      const float al = s_e[t];
#pragma unroll
      for (int j=0;j<8;j++) a[j] += al*h2f_u(cur[j]);
      cur = nxt;
    }
  }
  *(float4*)&s_part[wave][d0]   = make_float4(a[0],a[1],a[2],a[3]);
  *(float4*)&s_part[wave][d0+4] = make_float4(a[4],a[5],a[6],a[7]);
  __syncthreads();
  float vv = s_part[0][tid];
#pragma unroll
  for (int q=1;q<8;q++) vv += s_part[q][tid];
  u16 hh=f2bf_rn(vv), ll=f2bf_rn(vv-bf2f(hh));
  ctx_hi[(size_t)b*512 + tid] = hh;
  ctx_lo[(size_t)b*512 + tid] = ll;
}

// ---------------------------------------------------------------------------
// Fused gates GEMM + LSTM pointwise.  K=512 bf16x2 3-pass, BK=64.
// gates = ctx @ W_ih[:,:512]^T + combo[:,512:] (h-part precomputed).
// A (ctx planes) direct-from-global; B via LDS.  B row n = f*16+jj ->
// Bih row f*512+(j0+jj): fragment f holds gate f.  Epilogue: + combo +
// token adds, activations, c/h update; writes h planes + hid planes.
// ---------------------------------------------------------------------------
__global__ __launch_bounds__(256) void gates_lstm(
    const u16* __restrict__ Ah, const u16* __restrict__ Al,     // [512][512]
    const u16* __restrict__ Bh, const u16* __restrict__ Bl,     // [2048][512]
    const float* __restrict__ combo,                            // [512][2560]
    const float* __restrict__ WmT, const float* __restrict__ WbT,
    const int* __restrict__ midtok, const int* __restrict__ bottok,
    float* __restrict__ c,
    u16* __restrict__ hA_hi, u16* __restrict__ hA_lo,
    u16* __restrict__ hid_hi, u16* __restrict__ hid_lo, int s)
{
  constexpr int STR = 72;
  __shared__ short Bs[64*STR];
  const int tid=threadIdx.x, lane=tid&63, w=tid>>6;
  const int j0 = blockIdx.x*16, bm = blockIdx.y*64;
  const int mrow=lane&15, koff=(lane>>4)*8;
  const int arow = bm + w*16 + mrow;
  const int srow = tid>>2, scc=(tid&3)*8;
  const int sbrow = (srow>>4)*512 + j0 + (srow&15);

  f32x4v acc[4];
#pragma unroll
  for (int f=0;f<4;f++) acc[f] = (f32x4v){0.f,0.f,0.f,0.f};

  u16x8 sb0, sb1;
  bf16x8v a0[2], a1[2];
  auto loadB = [&](int it){
    const int pass = it>>3, kk=(it&7)<<6;
    const u16* Bp = (pass==1)?Bl:Bh;
    sb0 = *(const u16x8*)&Bp[(size_t)sbrow*512 + kk + scc];
    sb1 = *(const u16x8*)&Bp[(size_t)sbrow*512 + kk + scc + 32];
  };
  auto loadA0 = [&](int it){
    const int pass = it>>3, kk=(it&7)<<6;
    const u16* Ap = (pass==2)?Al:Ah;
    a0[0] = *(const bf16x8v*)&Ap[(size_t)arow*512 + kk + koff];
    a0[1] = *(const bf16x8v*)&Ap[(size_t)arow*512 + kk + koff + 32];
  };
  auto loadA1 = [&](int it){
    const int pass = it>>3, kk=(it&7)<<6;
    const u16* Ap = (pass==2)?Al:Ah;
    a1[0] = *(const bf16x8v*)&Ap[(size_t)arow*512 + kk + koff];
    a1[1] = *(const bf16x8v*)&Ap[(size_t)arow*512 + kk + koff + 32];
  };

  loadB(0); loadA0(0);
  for (int it=0; it<24; it+=2){
    __syncthreads();
    *(u16x8*)&Bs[srow*STR+scc]    = sb0;
    *(u16x8*)&Bs[srow*STR+scc+32] = sb1;
    if (it+1 < 24){ loadB(it+1); loadA1(it+1); }
    __syncthreads();
#pragma unroll
    for (int f=0;f<4;f++){
      bf16x8v b0 = *(const bf16x8v*)&Bs[(f*16+mrow)*STR + koff];
      bf16x8v b1 = *(const bf16x8v*)&Bs[(f*16+mrow)*STR + koff + 32];
      acc[f] = __builtin_amdgcn_mfma_f32_16x16x32_bf16(a0[0], b0, acc[f], 0,0,0);
      acc[f] = __builtin_amdgcn_mfma_f32_16x16x32_bf16(a0[1], b1, acc[f], 0,0,0);
    }
    if (it+1 >= 24) break;
    __syncthreads();
    *(u16x8*)&Bs[srow*STR+scc]    = sb0;
    *(u16x8*)&Bs[srow*STR+scc+32] = sb1;
    if (it+2 < 24){ loadB(it+2); loadA0(it+2); }
    __syncthreads();
#pragma unroll
    for (int f=0;f<4;f++){
      bf16x8v b0 = *(const bf16x8v*)&Bs[(f*16+mrow)*STR + koff];
      bf16x8v b1 = *(const bf16x8v*)&Bs[(f*16+mrow)*STR + koff + 32];
      acc[f] = __builtin_amdgcn_mfma_f32_16x16x32_bf16(a1[0], b0, acc[f], 0,0,0);
      acc[f] = __builtin_amdgcn_mfma_f32_16x16x32_bf16(a1[1], b1, acc[f], 0,0,0);
    }
  }

  // epilogue: lane holds gates f=0..3 for rows r0..r0+3 (b), col jj
  const int r0=(lane>>4)*4, jj=lane&15, j=j0+jj;
#pragma unroll
  for (int r=0;r<4;r++){
    const int b = bm + w*16 + r0 + r;
    const int mt = midtok[b*26 + s];
    const int bt = bottok[b*26 + s];
    const float* wm = WmT + (size_t)mt*2048;
    const float* wb = WbT + (size_t)bt*2048;
    const float* cb = combo + (size_t)b*2560 + 512;
    float ig = acc[0][r] + cb[j       ] + wm[j       ] + wb[j       ];
    float fg = acc[1][r] + cb[512 + j ] + wm[512 + j ] + wb[512 + j ];
    float gg = acc[2][r] + cb[1024 + j] + wm[1024 + j] + wb[1024 + j];
    float og = acc[3][r] + cb[1536 + j] + wm[1536 + j] + wb[1536 + j];
    ig = fast_sig(ig);
    fg = fast_sig(fg);
    gg = fast_tanh(gg);
    og = fast_sig(og);
    const size_t ci = (size_t)b*512 + j;
    const float cn = fg*c[ci] + ig*gg;
    const float hn = og*fast_tanh(cn);
    c[ci] = cn;
    u16 hh = f2bf_rn(hn), hl = f2bf_rn(hn - bf2f(hh));
    hA_hi[ci] = hh;
    hA_lo[ci] = hl;
    hid_hi[((size_t)s*512 + b)*512 + j] = hh;
    hid_lo[((size_t)s*512 + b)*512 + j] = hl;
  }
}

extern "C" void kernel_launch(void* const* d_in, const int* in_sizes, int n_in,
                              void* d_out, int out_size, void* d_ws, size_t ws_size,
                              hipStream_t stream) {
  const float* bH   = (const float*)d_in[0];
  const int*   midt = (const int*)  d_in[1];
  const int*   bott = (const int*)  d_in[2];
  const float* Wi2h = (const float*)d_in[3];
  const float* Wh2h = (const float*)d_in[4];
  const float* bh2h = (const float*)d_in[5];
  const float* Wsc  = (const float*)d_in[6];
  const float* Wih  = (const float*)d_in[7];
  const float* Whh  = (const float*)d_in[8];
  const float* bih  = (const float*)d_in[9];
  const float* bhh  = (const float*)d_in[10];
  const float* Wgen = (const float*)d_in[11];
  const float* bgen = (const float*)d_in[12];
  float* out = (float*)d_out;

  char* wp = (char*)d_ws;
  u16* projh   = (u16*)wp; wp += (size_t)B_*T_*H_*2;      // 67.1 MB fp16
  u16* bHh     = (u16*)wp; wp += (size_t)B_*T_*D_*2;      // 67.1 MB fp16
  u16* Bh2_hi  = (u16*)wp; wp += (size_t)2560*512*2;      // [W_h2h|W_hh] planes
  u16* Bh2_lo  = (u16*)wp; wp += (size_t)2560*512*2;
  u16* Bih_hi  = (u16*)wp; wp += (size_t)2048*512*2;      // W_ih[:, :512] planes
  u16* Bih_lo  = (u16*)wp; wp += (size_t)2048*512*2;
  u16* Wi2h_h  = (u16*)wp; wp += (size_t)512*512*2;       // fp16
  u16* Wg_hi   = (u16*)wp; wp += (size_t)64*512*2;
  u16* Wg_lo   = (u16*)wp; wp += (size_t)64*512*2;
  u16* ctx_hi  = (u16*)wp; wp += (size_t)B_*512*2;
  u16* ctx_lo  = (u16*)wp; wp += (size_t)B_*512*2;
  u16* hA_hi   = (u16*)wp; wp += (size_t)B_*512*2;
  u16* hA_lo   = (u16*)wp; wp += (size_t)B_*512*2;
  u16* hid_hi  = (u16*)wp; wp += (size_t)S_*B_*H_*2;      // 13.6 MB
  u16* hid_lo  = (u16*)wp; wp += (size_t)S_*B_*H_*2;
  float* combo = (float*)wp; wp += (size_t)B_*2560*4;     // 5.2 MB
  float* c     = (float*)wp; wp += (size_t)B_*H_*4;
  float* bcombF= (float*)wp; wp += (size_t)2560*4;
  float* WmT   = (float*)wp; wp += (size_t)MID_*2048*4;
  float* WbT   = (float*)wp; wp += (size_t)BOT_*2048*4;
  if ((size_t)(wp - (char*)d_ws) > ws_size) return;  // fail loudly

  hipMemsetAsync(hA_hi, 0, (size_t)B_*512*2, stream);
  hipMemsetAsync(hA_lo, 0, (size_t)B_*512*2, stream);
  hipMemsetAsync(c, 0, (size_t)B_*H_*4, stream);

  bcomb_kernel<<<10, 256, 0, stream>>>(bh2h, bih, bhh, bcombF);
  build_tokT<<<(MID_*2048+255)/256, 256, 0, stream>>>(Wih, WmT, WbT);
  cvt_plane<<<64,  256, 0, stream>>>(Wi2h, 512, 512, 512, 512, Wi2h_h, nullptr, 3);
  cvt_plane<<<64,  256, 0, stream>>>(Wh2h, 512, 512, 512, 512, Bh2_hi, Bh2_lo, 0);
  cvt_plane<<<256, 256, 0, stream>>>(Whh, 512, 2048, 2048, 512,
                                     Bh2_hi+(size_t)512*512, Bh2_lo+(size_t)512*512, 0);
  cvt_plane<<<256, 256, 0, stream>>>(Wih, XL_, 2048, 2048, 512, Bih_hi, Bih_lo, 0);
  cvt_plane<<<16,  256, 0, stream>>>(Wgen, 512, MID_, 64, 512, Wg_hi, Wg_lo, 0);

  // proj = fp16( batch_H @ W_i2h^T ) with fused bH->fp16 conversion + side-write
  gemm_proj<<<dim3(4,512), 256, 32768, stream>>>(bH, Wi2h_h, bHh, projh);

  for (int s=0; s<S_; ++s){
    // combo = h @ [W_h2h | W_hh]^T + [b_h2h | b_ih+b_hh]   (bf16x2, N=2560)
    gemm_bf<64,64,0><<<dim3(40,8), 256, 10240, stream>>>(
        hA_hi, hA_lo, 512, Bh2_hi, Bh2_lo, 512,
        combo, 2560, bcombF, 3, 16);
    attn_kernel<<<B_, 512, 0, stream>>>(
        projh, combo, Wsc, bHh, ctx_hi, ctx_lo);
    gates_lstm<<<dim3(32,8), 256, 0, stream>>>(
        ctx_hi, ctx_lo, Bih_hi, Bih_lo, combo, WmT, WbT,
        midt, bott, c, hA_hi, hA_lo,
        hid_hi, hid_lo, s);
  }

  // out = hid @ W_gen^T + b_gen  (bf16x2), M = S*B = 13312, N=64 (n<38 kept)
  gemm_bf<64,64,2><<<dim3(1,208), 256, 10240, stream>>>(
      hid_hi, hid_lo, 512, Wg_hi, Wg_lo, 512,
      out, 0, bgen, 3, 16);
}

// Round 8
// 1700.415 us; speedup vs baseline: 2.0749x; 1.0363x over previous
//
#include <hip/hip_runtime.h>
#include <hip/hip_bf16.h>
#include <hip/hip_fp16.h>
#include <cstdint>
#include <cstddef>

#define B_   512
#define T_   128
#define D_   512
#define H_   512
#define MID_ 38
#define BOT_ 38
#define S_   26
#define XL_  588   // D + MID + BOT = W_ih row length

typedef unsigned short u16;
typedef __attribute__((ext_vector_type(8))) short bf16x8v;
typedef __attribute__((ext_vector_type(8))) _Float16 f16x8v;
typedef __attribute__((ext_vector_type(8))) unsigned short u16x8;
typedef __attribute__((ext_vector_type(4))) float f32x4v;

__device__ __forceinline__ u16 f2bf_rn(float f){
  unsigned u = __float_as_uint(f);
  return (u16)((u + 0x7fffu + ((u>>16)&1u)) >> 16);
}
__device__ __forceinline__ float bf2f(u16 v){ return __uint_as_float(((unsigned)v)<<16); }
__device__ __forceinline__ u16 f2h_u(float f){ return __half_as_ushort(__float2half(f)); }
__device__ __forceinline__ float h2f_u(u16 u){ return __half2float(__ushort_as_half(u)); }

// branch-free fast transcendentals (v_exp_f32 + v_rcp_f32, ~1e-6 rel err)
__device__ __forceinline__ float fast_tanh(float x){
  return 1.0f - 2.0f*__builtin_amdgcn_rcpf(__expf(2.0f*x) + 1.0f);
}
__device__ __forceinline__ float fast_sig(float x){
  return __builtin_amdgcn_rcpf(1.0f + __expf(-x));
}

// ---------------------------------------------------------------------------
// fp32 -> 16-bit plane conversion, 512-col chunks, dest ld dld.
// mode 0: hi=bf16, lo=bf16 residual.  mode 3: hi=fp16 only.
// rows >= `rows` zero-padded up to padrows.
// ---------------------------------------------------------------------------
__global__ __launch_bounds__(256) void cvt_plane(
    const float* __restrict__ src, int ld, int rows, int padrows, int dld,
    u16* __restrict__ hi, u16* __restrict__ lo, int mode)
{
  const int n4 = padrows*128;
  for (int i = blockIdx.x*256 + threadIdx.x; i < n4; i += gridDim.x*256){
    const int row = i >> 7, c4 = (i & 127)*4;
    float4 v = make_float4(0.f,0.f,0.f,0.f);
    if (row < rows) v = *(const float4*)&src[(size_t)row*ld + c4];
    ushort4 h;
    if (mode == 3){
      h.x=f2h_u(v.x); h.y=f2h_u(v.y); h.z=f2h_u(v.z); h.w=f2h_u(v.w);
    } else {
      h.x=f2bf_rn(v.x); h.y=f2bf_rn(v.y); h.z=f2bf_rn(v.z); h.w=f2bf_rn(v.w);
    }
    *(ushort4*)&hi[(size_t)row*dld + c4] = h;
    if (mode == 0){
      ushort4 l;
      l.x=f2bf_rn(v.x-bf2f(h.x)); l.y=f2bf_rn(v.y-bf2f(h.y));
      l.z=f2bf_rn(v.z-bf2f(h.z)); l.w=f2bf_rn(v.w-bf2f(h.w));
      *(ushort4*)&lo[(size_t)row*dld + c4] = l;
    }
  }
}

// token-column tables, transposed for coalesced epilogue reads
__global__ __launch_bounds__(256) void build_tokT(
    const float* __restrict__ Wih, float* __restrict__ WmT, float* __restrict__ WbT)
{
  int i = blockIdx.x*256 + threadIdx.x;   // over 38*2048
  if (i < MID_*2048){
    int c = i >> 11, j = i & 2047;
    WmT[i] = Wih[(size_t)j*XL_ + 512 + c];
    WbT[i] = Wih[(size_t)j*XL_ + 512 + MID_ + c];
  }
}

// bcombF[0:512] = b_h2h; bcombF[512+j] = b_ih[j] + b_hh[j]
__global__ __launch_bounds__(256) void bcomb_kernel(
    const float* __restrict__ bh2h, const float* __restrict__ bih,
    const float* __restrict__ bhh, float* __restrict__ o)
{
  int i = blockIdx.x*256 + threadIdx.x;
  if (i < 512) o[i] = bh2h[i];
  else if (i < 2560) o[i] = bih[i-512] + bhh[i-512];
}

// ---------------------------------------------------------------------------
// proj GEMM, XCD-aware 1D grid (2048 blocks): n -> x=n&7 (XCD slot),
// q=n>>3; bn=(q&3), bm=(q>>2)*8+x.  The 4 bn-blocks of one A row-panel run
// back-to-back on the SAME XCD -> A tile fetched from HBM once, L2-reused.
// A = batch_H fp32 -> fp16 conversion fused in staging; bn==0 blocks
// side-write fp16 A to bHh.  B = Wi2h fp16.  C = fp16 projh via LDS bounce.
// ---------------------------------------------------------------------------
__global__ __launch_bounds__(256) void gemm_proj(
    const float* __restrict__ A, const u16* __restrict__ Bh,
    u16* __restrict__ bHh, u16* __restrict__ projh)
{
  extern __shared__ char smem[];
  constexpr int STR = 40;
  short* As = (short*)smem;                  // [128][STR]
  short* Bs = As + 128*STR;
  const int tid=threadIdx.x;
  const int n = blockIdx.x;
  const int x = n & 7, q = n >> 3;
  const int bn = (q & 3) * 128;
  const int bm = ((q >> 2)*8 + x) * 128;
  const int w=tid>>6, lane=tid&63, wr=w>>1, wc=w&1;
  const bool wrA = ((q & 3) == 0);

  f32x4v acc[4][4];
#pragma unroll
  for (int i=0;i<4;i++)
#pragma unroll
    for (int j=0;j<4;j++) acc[i][j] = (f32x4v){0.f,0.f,0.f,0.f};

  float4 fa[2][2];
  u16x8 rb[2];
  auto load = [&](int it){
    const int kk = it<<5;
#pragma unroll
    for (int L=0; L<2; L++){
      int t=L*256+tid, row=t>>2, c=(t&3)*8;
      const float* p = &A[(size_t)(bm+row)*512 + kk + c];
      fa[L][0] = *(const float4*)p;
      fa[L][1] = *(const float4*)(p+4);
      rb[L] = *(const u16x8*)&Bh[(size_t)(bn+(t>>2))*512 + kk + c];
    }
  };
  load(0);

  for (int it=0; it<16; ++it){
    const int kk = it<<5;
    __syncthreads();
#pragma unroll
    for (int L=0; L<2; L++){
      int t=L*256+tid, row=t>>2, c=(t&3)*8;
      u16x8 hv;
      hv[0]=f2h_u(fa[L][0].x); hv[1]=f2h_u(fa[L][0].y);
      hv[2]=f2h_u(fa[L][0].z); hv[3]=f2h_u(fa[L][0].w);
      hv[4]=f2h_u(fa[L][1].x); hv[5]=f2h_u(fa[L][1].y);
      hv[6]=f2h_u(fa[L][1].z); hv[7]=f2h_u(fa[L][1].w);
      *(u16x8*)&As[row*STR+c] = hv;
      if (wrA) *(u16x8*)&bHh[(size_t)(bm+row)*512 + kk + c] = hv;
      *(u16x8*)&Bs[row*STR+c] = rb[L];
    }
    if (it+1 < 16) load(it+1);
    __syncthreads();
    const int koff = (lane>>4)*8, mrow = lane&15;
#pragma unroll
    for (int i=0;i<4;i++)
#pragma unroll
      for (int j=0;j<4;j++){
        f16x8v af = *(const f16x8v*)&As[(wr*64+i*16+mrow)*STR + koff];
        f16x8v bf = *(const f16x8v*)&Bs[(wc*64+j*16+mrow)*STR + koff];
        acc[i][j] = __builtin_amdgcn_mfma_f32_16x16x32_f16(af, bf, acc[i][j], 0,0,0);
      }
  }

  // epilogue: fp16 out via LDS bounce
  const int r0 = (lane>>4)*4, cn = lane&15;
  __syncthreads();
  u16* Ts = (u16*)smem;   // [128][128]
#pragma unroll
  for (int i=0;i<4;i++)
#pragma unroll
    for (int j=0;j<4;j++)
#pragma unroll
      for (int r=0;r<4;r++)
        Ts[(wr*64+i*16+r0+r)*128 + wc*64+j*16+cn] = f2h_u(acc[i][j][r]);
  __syncthreads();
#pragma unroll
  for (int q2=0;q2<8;q2++){
    int idx = q2*256 + tid;
    int row = idx>>4, c8 = (idx&15)*8;
    *(float4*)&projh[(size_t)(bm+row)*512 + bn + c8] = *(const float4*)&Ts[row*128 + c8];
  }
}

// ---------------------------------------------------------------------------
// bf16 MFMA GEMM (hcombo and generator), K = kSteps*32, NT, bf16x2 3-pass.
// MODE 0: fp32 out + col-bias.  MODE 2: generator out (m->(s,b), n<38, +bias2).
// ---------------------------------------------------------------------------
template<int BM,int BN,int MODE>
__global__ __launch_bounds__(256) void gemm_bf(
    const u16* __restrict__ Ah, const u16* __restrict__ Al, int lda,
    const u16* __restrict__ Bh, const u16* __restrict__ Bl, int ldb,
    float* __restrict__ Cout, int ldc,
    const float* __restrict__ bias2, int npass, int kSteps)
{
  extern __shared__ char smem[];
  constexpr int STR = 40;
  short* As = (short*)smem;                  // [BM][STR]
  short* Bs = As + BM*STR;                   // [BN][STR]
  const int tid=threadIdx.x, bm=blockIdx.y*BM, bn=blockIdx.x*BN;
  const int w=tid>>6, lane=tid&63, wr=w>>1, wc=w&1;
  constexpr int WM=BM/2, WN=BN/2, FM=WM/16, FN=WN/16;
  constexpr int LA=BM/64, LB=BN/64;
  const int nIter = npass*kSteps;

  f32x4v acc[FM][FN];
#pragma unroll
  for (int i=0;i<FM;i++)
#pragma unroll
    for (int j=0;j<FN;j++) acc[i][j] = (f32x4v){0.f,0.f,0.f,0.f};

  u16x8 ra[LA], rb[LB];
  auto load = [&](int it){
    const int pass = it/kSteps, kk = (it%kSteps)<<5;
    const u16* Ap = (pass==2)?Al:Ah;
    const u16* Bp = (pass==1)?Bl:Bh;
#pragma unroll
    for (int L=0; L<LA; L++){
      int t=L*256+tid, row=t>>2, c=(t&3)*8;
      ra[L] = *(const u16x8*)&Ap[(size_t)(bm+row)*lda + kk + c];
    }
#pragma unroll
    for (int L=0; L<LB; L++){
      int t=L*256+tid, row=t>>2, c=(t&3)*8;
      rb[L] = *(const u16x8*)&Bp[(size_t)(bn+row)*ldb + kk + c];
    }
  };
  load(0);

  for (int it=0; it<nIter; ++it){
    __syncthreads();
#pragma unroll
    for (int L=0; L<LA; L++){ int t=L*256+tid; *(u16x8*)&As[(t>>2)*STR+(t&3)*8] = ra[L]; }
#pragma unroll
    for (int L=0; L<LB; L++){ int t=L*256+tid; *(u16x8*)&Bs[(t>>2)*STR+(t&3)*8] = rb[L]; }
    if (it+1 < nIter) load(it+1);
    __syncthreads();
    const int koff = (lane>>4)*8, mrow = lane&15;
#pragma unroll
    for (int i=0;i<FM;i++)
#pragma unroll
      for (int j=0;j<FN;j++){
        bf16x8v af = *(const bf16x8v*)&As[(wr*WM+i*16+mrow)*STR + koff];
        bf16x8v bf = *(const bf16x8v*)&Bs[(wc*WN+j*16+mrow)*STR + koff];
        acc[i][j] = __builtin_amdgcn_mfma_f32_16x16x32_bf16(af, bf, acc[i][j], 0,0,0);
      }
  }

  const int r0 = (lane>>4)*4, cn = lane&15;
  if constexpr (MODE==2){
#pragma unroll
    for (int i=0;i<FM;i++)
#pragma unroll
      for (int j=0;j<FN;j++)
#pragma unroll
        for (int r=0;r<4;r++){
          int m = bm + wr*WM + i*16 + r0 + r;       // m = s*512 + b
          int n = bn + wc*WN + j*16 + cn;
          if (n < MID_){
            int s = m >> 9, b = m & 511;
            Cout[((size_t)b*S_ + s)*MID_ + n] = acc[i][j][r] + bias2[n];
          }
        }
  } else {
#pragma unroll
    for (int i=0;i<FM;i++)
#pragma unroll
      for (int j=0;j<FN;j++)
#pragma unroll
        for (int r=0;r<4;r++){
          int row = bm + wr*WM + i*16 + r0 + r;
          int col = bn + wc*WN + j*16 + cn;
          float v = acc[i][j][r];
          if (bias2) v += bias2[col];
          Cout[(size_t)row*ldc + col] = v;
        }
  }
}

// ---------------------------------------------------------------------------
// Fused attention, 1024 threads (16 waves, 2 blocks/CU = full occupancy):
//   pp from combo[b][0:512] (fp32, ld 2560)
//   e[t] = sum_h Ws[h]*fast_tanh(projh[b,t,h]+pp[h]); softmax over t;
//   ctx[b,d] = sum_t alpha[t]*bHh[b,t,d] -> ctx hi/lo planes.
// ---------------------------------------------------------------------------
__global__ __launch_bounds__(1024) void attn_kernel(
    const u16* __restrict__ projh, const float* __restrict__ combo,
    const float* __restrict__ Wscore, const u16* __restrict__ bHh,
    u16* __restrict__ ctx_hi, u16* __restrict__ ctx_lo)
{
  __shared__ float s_e[T_];
  __shared__ float s_red[32];
  __shared__ float s_part[16][D_];
  const int tid=threadIdx.x, b=blockIdx.x, wave=tid>>6, lane=tid&63;

  float pv[8], wv[8];
  {
    const float* pprow = combo + (size_t)b*2560;
    float4 p0=*(const float4*)&pprow[lane*8], p1=*(const float4*)&pprow[lane*8+4];
    float4 w0=*(const float4*)&Wscore[lane*8], w1=*(const float4*)&Wscore[lane*8+4];
    pv[0]=p0.x;pv[1]=p0.y;pv[2]=p0.z;pv[3]=p0.w;pv[4]=p1.x;pv[5]=p1.y;pv[6]=p1.z;pv[7]=p1.w;
    wv[0]=w0.x;wv[1]=w0.y;wv[2]=w0.z;wv[3]=w0.w;wv[4]=w1.x;wv[5]=w1.y;wv[6]=w1.z;wv[7]=w1.w;
  }
  // e-phase: wave w handles t = w, w+16, ... (8 rows); 2-deep pipeline
  {
    const u16* base = projh + (size_t)b*T_*H_ + lane*8;
    u16x8 cur = *(const u16x8*)(base + (size_t)wave*H_);
    for (int t=wave; t<T_; t+=16){
      u16x8 nxt;
      if (t+16 < T_) nxt = *(const u16x8*)(base + (size_t)(t+16)*H_);
      float acc = 0.f;
#pragma unroll
      for (int j=0;j<8;j++) acc += wv[j]*fast_tanh(h2f_u(cur[j]) + pv[j]);
#pragma unroll
      for (int o=32;o>0;o>>=1) acc += __shfl_down(acc,o);
      if (lane==0) s_e[t] = acc;
      cur = nxt;
    }
  }
  __syncthreads();
  // softmax over s_e[0..127]
  float v = (tid < T_) ? s_e[tid] : -INFINITY;
  float m = v;
#pragma unroll
  for (int o=32;o>0;o>>=1) m = fmaxf(m, __shfl_down(m,o));
  if (tid < T_ && lane==0) s_red[wave] = m;      // waves 0,1 write
  __syncthreads();
  m = fmaxf(s_red[0], s_red[1]);
  float p = (tid < T_) ? __expf(v - m) : 0.f;
  float sum = p;
#pragma unroll
  for (int o=32;o>0;o>>=1) sum += __shfl_down(sum,o);
  if (tid < T_ && lane==0) s_red[16+wave] = sum;
  __syncthreads();
  float denom = s_red[16] + s_red[17];
  if (tid < T_) s_e[tid] = p/denom;
  __syncthreads();

  // context: wave w covers t in [8w, 8w+8); lane covers d = lane*8..+7
  const int d0 = lane*8;
  float a[8] = {0,0,0,0,0,0,0,0};
  {
    const u16* base = bHh + (size_t)b*T_*D_ + d0;
    u16x8 cur = *(const u16x8*)(base + (size_t)(wave*8)*D_);
    for (int t=wave*8; t<wave*8+8; ++t){
      u16x8 nxt;
      if (t+1 < wave*8+8) nxt = *(const u16x8*)(base + (size_t)(t+1)*D_);
      const float al = s_e[t];
#pragma unroll
      for (int j=0;j<8;j++) a[j] += al*h2f_u(cur[j]);
      cur = nxt;
    }
  }
  *(float4*)&s_part[wave][d0]   = make_float4(a[0],a[1],a[2],a[3]);
  *(float4*)&s_part[wave][d0+4] = make_float4(a[4],a[5],a[6],a[7]);
  __syncthreads();
  if (tid < D_){
    float vv = s_part[0][tid];
#pragma unroll
    for (int q=1;q<16;q++) vv += s_part[q][tid];
    u16 hh=f2bf_rn(vv), ll=f2bf_rn(vv-bf2f(hh));
    ctx_hi[(size_t)b*512 + tid] = hh;
    ctx_lo[(size_t)b*512 + tid] = ll;
  }
}

// ---------------------------------------------------------------------------
// Fused gates GEMM + LSTM pointwise.  K=512 bf16x2 3-pass, BK=64.
// gates = ctx @ W_ih[:,:512]^T + combo[:,512:] (h-part precomputed).
// A (ctx planes) direct-from-global; B via LDS.  B row n = f*16+jj ->
// Bih row f*512+(j0+jj): fragment f holds gate f.  Epilogue: + combo +
// token adds, activations, c/h update; writes h planes + hid planes.
// ---------------------------------------------------------------------------
__global__ __launch_bounds__(256) void gates_lstm(
    const u16* __restrict__ Ah, const u16* __restrict__ Al,     // [512][512]
    const u16* __restrict__ Bh, const u16* __restrict__ Bl,     // [2048][512]
    const float* __restrict__ combo,                            // [512][2560]
    const float* __restrict__ WmT, const float* __restrict__ WbT,
    const int* __restrict__ midtok, const int* __restrict__ bottok,
    float* __restrict__ c,
    u16* __restrict__ hA_hi, u16* __restrict__ hA_lo,
    u16* __restrict__ hid_hi, u16* __restrict__ hid_lo, int s)
{
  constexpr int STR = 72;
  __shared__ short Bs[64*STR];
  const int tid=threadIdx.x, lane=tid&63, w=tid>>6;
  const int j0 = blockIdx.x*16, bm = blockIdx.y*64;
  const int mrow=lane&15, koff=(lane>>4)*8;
  const int arow = bm + w*16 + mrow;
  const int srow = tid>>2, scc=(tid&3)*8;
  const int sbrow = (srow>>4)*512 + j0 + (srow&15);

  f32x4v acc[4];
#pragma unroll
  for (int f=0;f<4;f++) acc[f] = (f32x4v){0.f,0.f,0.f,0.f};

  u16x8 sb0, sb1;
  bf16x8v a0[2], a1[2];
  auto loadB = [&](int it){
    const int pass = it>>3, kk=(it&7)<<6;
    const u16* Bp = (pass==1)?Bl:Bh;
    sb0 = *(const u16x8*)&Bp[(size_t)sbrow*512 + kk + scc];
    sb1 = *(const u16x8*)&Bp[(size_t)sbrow*512 + kk + scc + 32];
  };
  auto loadA0 = [&](int it){
    const int pass = it>>3, kk=(it&7)<<6;
    const u16* Ap = (pass==2)?Al:Ah;
    a0[0] = *(const bf16x8v*)&Ap[(size_t)arow*512 + kk + koff];
    a0[1] = *(const bf16x8v*)&Ap[(size_t)arow*512 + kk + koff + 32];
  };
  auto loadA1 = [&](int it){
    const int pass = it>>3, kk=(it&7)<<6;
    const u16* Ap = (pass==2)?Al:Ah;
    a1[0] = *(const bf16x8v*)&Ap[(size_t)arow*512 + kk + koff];
    a1[1] = *(const bf16x8v*)&Ap[(size_t)arow*512 + kk + koff + 32];
  };

  loadB(0); loadA0(0);
  for (int it=0; it<24; it+=2){
    __syncthreads();
    *(u16x8*)&Bs[srow*STR+scc]    = sb0;
    *(u16x8*)&Bs[srow*STR+scc+32] = sb1;
    if (it+1 < 24){ loadB(it+1); loadA1(it+1); }
    __syncthreads();
#pragma unroll
    for (int f=0;f<4;f++){
      bf16x8v b0 = *(const bf16x8v*)&Bs[(f*16+mrow)*STR + koff];
      bf16x8v b1 = *(const bf16x8v*)&Bs[(f*16+mrow)*STR + koff + 32];
      acc[f] = __builtin_amdgcn_mfma_f32_16x16x32_bf16(a0[0], b0, acc[f], 0,0,0);
      acc[f] = __builtin_amdgcn_mfma_f32_16x16x32_bf16(a0[1], b1, acc[f], 0,0,0);
    }
    if (it+1 >= 24) break;
    __syncthreads();
    *(u16x8*)&Bs[srow*STR+scc]    = sb0;
    *(u16x8*)&Bs[srow*STR+scc+32] = sb1;
    if (it+2 < 24){ loadB(it+2); loadA0(it+2); }
    __syncthreads();
#pragma unroll
    for (int f=0;f<4;f++){
      bf16x8v b0 = *(const bf16x8v*)&Bs[(f*16+mrow)*STR + koff];
      bf16x8v b1 = *(const bf16x8v*)&Bs[(f*16+mrow)*STR + koff + 32];
      acc[f] = __builtin_amdgcn_mfma_f32_16x16x32_bf16(a1[0], b0, acc[f], 0,0,0);
      acc[f] = __builtin_amdgcn_mfma_f32_16x16x32_bf16(a1[1], b1, acc[f], 0,0,0);
    }
  }

  // epilogue: lane holds gates f=0..3 for rows r0..r0+3 (b), col jj
  const int r0=(lane>>4)*4, jj=lane&15, j=j0+jj;
#pragma unroll
  for (int r=0;r<4;r++){
    const int b = bm + w*16 + r0 + r;
    const int mt = midtok[b*26 + s];
    const int bt = bottok[b*26 + s];
    const float* wm = WmT + (size_t)mt*2048;
    const float* wb = WbT + (size_t)bt*2048;
    const float* cb = combo + (size_t)b*2560 + 512;
    float ig = acc[0][r] + cb[j       ] + wm[j       ] + wb[j       ];
    float fg = acc[1][r] + cb[512 + j ] + wm[512 + j ] + wb[512 + j ];
    float gg = acc[2][r] + cb[1024 + j] + wm[1024 + j] + wb[1024 + j];
    float og = acc[3][r] + cb[1536 + j] + wm[1536 + j] + wb[1536 + j];
    ig = fast_sig(ig);
    fg = fast_sig(fg);
    gg = fast_tanh(gg);
    og = fast_sig(og);
    const size_t ci = (size_t)b*512 + j;
    const float cn = fg*c[ci] + ig*gg;
    const float hn = og*fast_tanh(cn);
    c[ci] = cn;
    u16 hh = f2bf_rn(hn), hl = f2bf_rn(hn - bf2f(hh));
    hA_hi[ci] = hh;
    hA_lo[ci] = hl;
    hid_hi[((size_t)s*512 + b)*512 + j] = hh;
    hid_lo[((size_t)s*512 + b)*512 + j] = hl;
  }
}

extern "C" void kernel_launch(void* const* d_in, const int* in_sizes, int n_in,
                              void* d_out, int out_size, void* d_ws, size_t ws_size,
                              hipStream_t stream) {
  const float* bH   = (const float*)d_in[0];
  const int*   midt = (const int*)  d_in[1];
  const int*   bott = (const int*)  d_in[2];
  const float* Wi2h = (const float*)d_in[3];
  const float* Wh2h = (const float*)d_in[4];
  const float* bh2h = (const float*)d_in[5];
  const float* Wsc  = (const float*)d_in[6];
  const float* Wih  = (const float*)d_in[7];
  const float* Whh  = (const float*)d_in[8];
  const float* bih  = (const float*)d_in[9];
  const float* bhh  = (const float*)d_in[10];
  const float* Wgen = (const float*)d_in[11];
  const float* bgen = (const float*)d_in[12];
  float* out = (float*)d_out;

  char* wp = (char*)d_ws;
  u16* projh   = (u16*)wp; wp += (size_t)B_*T_*H_*2;      // 67.1 MB fp16
  u16* bHh     = (u16*)wp; wp += (size_t)B_*T_*D_*2;      // 67.1 MB fp16
  u16* Bh2_hi  = (u16*)wp; wp += (size_t)2560*512*2;      // [W_h2h|W_hh] planes
  u16* Bh2_lo  = (u16*)wp; wp += (size_t)2560*512*2;
  u16* Bih_hi  = (u16*)wp; wp += (size_t)2048*512*2;      // W_ih[:, :512] planes
  u16* Bih_lo  = (u16*)wp; wp += (size_t)2048*512*2;
  u16* Wi2h_h  = (u16*)wp; wp += (size_t)512*512*2;       // fp16
  u16* Wg_hi   = (u16*)wp; wp += (size_t)64*512*2;
  u16* Wg_lo   = (u16*)wp; wp += (size_t)64*512*2;
  u16* ctx_hi  = (u16*)wp; wp += (size_t)B_*512*2;
  u16* ctx_lo  = (u16*)wp; wp += (size_t)B_*512*2;
  u16* hA_hi   = (u16*)wp; wp += (size_t)B_*512*2;
  u16* hA_lo   = (u16*)wp; wp += (size_t)B_*512*2;
  u16* hid_hi  = (u16*)wp; wp += (size_t)S_*B_*H_*2;      // 13.6 MB
  u16* hid_lo  = (u16*)wp; wp += (size_t)S_*B_*H_*2;
  float* combo = (float*)wp; wp += (size_t)B_*2560*4;     // 5.2 MB
  float* c     = (float*)wp; wp += (size_t)B_*H_*4;
  float* bcombF= (float*)wp; wp += (size_t)2560*4;
  float* WmT   = (float*)wp; wp += (size_t)MID_*2048*4;
  float* WbT   = (float*)wp; wp += (size_t)BOT_*2048*4;
  if ((size_t)(wp - (char*)d_ws) > ws_size) return;  // fail loudly

  hipMemsetAsync(hA_hi, 0, (size_t)B_*512*2, stream);
  hipMemsetAsync(hA_lo, 0, (size_t)B_*512*2, stream);
  hipMemsetAsync(c, 0, (size_t)B_*H_*4, stream);

  bcomb_kernel<<<10, 256, 0, stream>>>(bh2h, bih, bhh, bcombF);
  build_tokT<<<(MID_*2048+255)/256, 256, 0, stream>>>(Wih, WmT, WbT);
  cvt_plane<<<64,  256, 0, stream>>>(Wi2h, 512, 512, 512, 512, Wi2h_h, nullptr, 3);
  cvt_plane<<<64,  256, 0, stream>>>(Wh2h, 512, 512, 512, 512, Bh2_hi, Bh2_lo, 0);
  cvt_plane<<<256, 256, 0, stream>>>(Whh, 512, 2048, 2048, 512,
                                     Bh2_hi+(size_t)512*512, Bh2_lo+(size_t)512*512, 0);
  cvt_plane<<<256, 256, 0, stream>>>(Wih, XL_, 2048, 2048, 512, Bih_hi, Bih_lo, 0);
  cvt_plane<<<16,  256, 0, stream>>>(Wgen, 512, MID_, 64, 512, Wg_hi, Wg_lo, 0);

  // proj = fp16( batch_H @ W_i2h^T ), XCD-aware 1D grid, fused bH conversion
  gemm_proj<<<2048, 256, 32768, stream>>>(bH, Wi2h_h, bHh, projh);

  for (int s=0; s<S_; ++s){
    // combo = h @ [W_h2h | W_hh]^T + [b_h2h | b_ih+b_hh]   (bf16x2, N=2560)
    gemm_bf<64,64,0><<<dim3(40,8), 256, 10240, stream>>>(
        hA_hi, hA_lo, 512, Bh2_hi, Bh2_lo, 512,
        combo, 2560, bcombF, 3, 16);
    attn_kernel<<<B_, 1024, 0, stream>>>(
        projh, combo, Wsc, bHh, ctx_hi, ctx_lo);
    gates_lstm<<<dim3(32,8), 256, 0, stream>>>(
        ctx_hi, ctx_lo, Bih_hi, Bih_lo, combo, WmT, WbT,
        midt, bott, c, hA_hi, hA_lo,
        hid_hi, hid_lo, s);
  }

  // out = hid @ W_gen^T + b_gen  (bf16x2), M = S*B = 13312, N=64 (n<38 kept)
  gemm_bf<64,64,2><<<dim3(1,208), 256, 10240, stream>>>(
      hid_hi, hid_lo, 512, Wg_hi, Wg_lo, 512,
      out, 0, bgen, 3, 16);
}